// Round 4
// baseline (200.830 us; speedup 1.0000x reference)
//
#include <hip/hip_runtime.h>
#include <hip/hip_bf16.h>
#include <math.h>

// R4: 6 dispatches. gemmI reads NCHW x directly; sample+outGEMM fused; y bf16.

using bf16x8 = __attribute__((ext_vector_type(8))) short;
using f32x4  = __attribute__((ext_vector_type(4))) float;

#define GLOBAL_AS __attribute__((address_space(1)))
#define LDS_AS    __attribute__((address_space(3)))

static __device__ inline void g2lds16(const void* g, void* l) {
  __builtin_amdgcn_global_load_lds((const GLOBAL_AS int*)g, (LDS_AS int*)l, 16, 0, 0);
}
static __device__ inline unsigned short f2bf(float v) {
  __hip_bfloat16 b = __float2bfloat16(v);
  return *reinterpret_cast<unsigned short*>(&b);
}
static __device__ inline float us2f(unsigned short u) {
  union { unsigned u; float f; } c; c.u = ((unsigned)u) << 16; return c.f;
}

// ---------------- weight prep: W[k][n] fp32 -> Bt[n][k] bf16 (+pad) ---------
__global__ __launch_bounds__(256) void prep_k(
    const float* __restrict__ inp_w, const float* __restrict__ off_w,
    const float* __restrict__ off_b, const float* __restrict__ mask_w,
    const float* __restrict__ mask_b, const float* __restrict__ out_w,
    __hip_bfloat16* __restrict__ BtI, __hip_bfloat16* __restrict__ BtOM,
    __hip_bfloat16* __restrict__ BtO, float* __restrict__ bOM)
{
  int b = blockIdx.x, t = threadIdx.x;   // t = k index
  if (b < 256) {
    int n = b;
    BtI[n * 256 + t] = __float2bfloat16(inp_w[t * 256 + n]);
  } else if (b < 768) {
    int n = b - 256;
    float v = 0.f;
    if (n < 288) v = off_w[t * 288 + n];
    else if (n < 432) v = mask_w[t * 144 + (n - 288)];
    BtOM[n * 256 + t] = __float2bfloat16(v);
    if (b == 256) {
      for (int idx = t; idx < 512; idx += 256) {
        float bv = (idx < 288) ? off_b[idx] : ((idx < 432) ? mask_b[idx - 288] : 0.f);
        bOM[idx] = bv;
      }
    }
  } else {
    int n = b - 768;
    BtO[n * 256 + t] = __float2bfloat16(out_w[t * 256 + n]);
  }
}

// ---------------- MFMA GEMM -> bf16 row-major C -----------------------------
// ASRC 0: A = bf16 [m][256] (g2lds16 direct).
// ASRC 1: A = x NCHW fp32; stage fp32 [k][128] tile, cvt in fragment build.
template<int ASRC>
__global__ __launch_bounds__(256) void gemm_mfma(
    const void* __restrict__ Av, const __hip_bfloat16* __restrict__ Bt,
    const float* __restrict__ bias, __hip_bfloat16* __restrict__ C,
    int ldc, int nstore)
{
  constexpr int ABYTES = ASRC ? 16384 : 8192;
  __shared__ __align__(16) char smem[ABYTES + 8192];
  short* As  = (short*)smem;
  float* Asf = (float*)smem;
  short* Bs  = (short*)(smem + ABYTES);
  const int t = threadIdx.x;
  const int wave = t >> 6, lane = t & 63;
  const int quad = lane >> 4, lr = lane & 15;
  const int wm = wave >> 1, wn = wave & 1;
  const size_t m0 = (size_t)blockIdx.y * 128;
  const int n0 = blockIdx.x * 128;
  const int n4 = (int)(m0 >> 12), hw0 = (int)(m0 & 4095);

  f32x4 acc[4][4];
  #pragma unroll
  for (int i = 0; i < 4; ++i)
    #pragma unroll
    for (int j = 0; j < 4; ++j)
      acc[i][j] = (f32x4){0.f, 0.f, 0.f, 0.f};

  for (int kt = 0; kt < 256; kt += 32) {
    if (ASRC == 0) {
      const __hip_bfloat16* A = (const __hip_bfloat16*)Av;
      #pragma unroll
      for (int j = 0; j < 2; ++j) {
        int chunk = j * 64 + lane;
        int row = wave * 32 + (chunk >> 2), kq = chunk & 3;
        g2lds16(A + (m0 + row) * 256 + kt + kq * 8,
                (char*)As + wave * 2048 + j * 1024 + (lane & 63) * 16 - lane * 16 + lane * 16);
      }
    } else {
      const float* X = (const float*)Av;
      #pragma unroll
      for (int j = 0; j < 4; ++j) {
        int krow = wave * 8 + j * 2 + (lane >> 5);
        int px4 = (lane & 31) * 4;
        g2lds16(X + (size_t)n4 * 1048576 + (size_t)(kt + krow) * 4096 + hw0 + px4,
                (char*)smem + wave * 4096 + j * 1024 + lane * 16);
      }
    }
    {  // B staging (both modes)
      #pragma unroll
      for (int j = 0; j < 2; ++j) {
        int chunk = j * 64 + lane;
        int row = wave * 32 + (chunk >> 2), kq = chunk & 3;
        g2lds16(Bt + (size_t)(n0 + row) * 256 + kt + kq * 8,
                (char*)Bs + wave * 2048 + j * 1024 + lane * 16);
      }
    }
    __syncthreads();
    bf16x8 bfv[4];
    #pragma unroll
    for (int ni = 0; ni < 4; ++ni)
      bfv[ni] = *(const bf16x8*)&Bs[(wn * 64 + ni * 16 + lr) * 32 + quad * 8];
    #pragma unroll
    for (int mi = 0; mi < 4; ++mi) {
      bf16x8 af;
      if (ASRC == 0) {
        af = *(const bf16x8*)&As[(wm * 64 + mi * 16 + lr) * 32 + quad * 8];
      } else {
        int m = wm * 64 + mi * 16 + lr;
        #pragma unroll
        for (int j2 = 0; j2 < 8; ++j2)
          ((unsigned short*)&af)[j2] = f2bf(Asf[(quad * 8 + j2) * 128 + m]);
      }
      #pragma unroll
      for (int ni = 0; ni < 4; ++ni)
        acc[mi][ni] = __builtin_amdgcn_mfma_f32_16x16x32_bf16(af, bfv[ni], acc[mi][ni], 0, 0, 0);
    }
    __syncthreads();
  }

  #pragma unroll
  for (int mi = 0; mi < 4; ++mi) {
    #pragma unroll
    for (int ni = 0; ni < 4; ++ni) {
      int col = n0 + wn * 64 + ni * 16 + lr;
      if (col < nstore) {
        float bv = bias[col];
        #pragma unroll
        for (int reg = 0; reg < 4; ++reg) {
          size_t m = m0 + wm * 64 + mi * 16 + quad * 4 + reg;
          C[m * ldc + col] = __float2bfloat16(acc[mi][ni][reg] + bv);
        }
      }
    }
  }
}

// ---------------- depthwise 3x3: block per (n,c) plane, fp32 x -> bf16 y ----
__global__ __launch_bounds__(256) void dwconv_k(
    const float* __restrict__ x, const float* __restrict__ dw_w,
    const float* __restrict__ dw_b, __hip_bfloat16* __restrict__ y)
{
  __shared__ float pl[4096];            // 64x64 plane
  const int bc = blockIdx.x;
  const int n4 = bc >> 8, c = bc & 255;
  const int t = threadIdx.x;
  const float* xc = x + (size_t)n4 * 1048576 + (size_t)c * 4096;
  #pragma unroll
  for (int r = 0; r < 4; ++r) {
    int idx4 = t + r * 256;
    *(float4*)&pl[idx4 * 4] = *(const float4*)&xc[idx4 * 4];
  }
  float wv[9];
  #pragma unroll
  for (int i = 0; i < 9; ++i) wv[i] = dw_w[c * 9 + i];
  const float bb = dw_b[c];
  __syncthreads();
  __hip_bfloat16* yc = y + (size_t)(n4 * 256 + c) * 4096;
  #pragma unroll 4
  for (int r = 0; r < 16; ++r) {
    int px = t + r * 256;
    int h = px >> 6, w = px & 63;
    float s = bb;
    #pragma unroll
    for (int dh = -1; dh <= 1; ++dh) {
      int hh = h + dh;
      if ((unsigned)hh >= 64u) continue;
      #pragma unroll
      for (int dw = -1; dw <= 1; ++dw) {
        int ww = w + dw;
        if ((unsigned)ww >= 64u) continue;
        s = fmaf(pl[hh * 64 + ww], wv[(dh + 1) * 3 + (dw + 1)], s);
      }
    }
    yc[px] = __float2bfloat16(s);
  }
}

// ---------------- LayerNorm(C) + GELU: y bf16 NCHW -> x1 bf16 [pix][c] ------
__global__ __launch_bounds__(256) void ln_k(
    const __hip_bfloat16* __restrict__ y, const float* __restrict__ ln_g,
    const float* __restrict__ ln_b, __hip_bfloat16* __restrict__ x1)
{
  __shared__ float ps[4][64], pq[4][64], mu_s[64], rs_s[64];
  __shared__ unsigned short st[256 * 65];
  const int blk = blockIdx.x;
  const int n4 = blk >> 6, h = blk & 63;
  const int t = threadIdx.x;
  const int w = t & 63, cq = t >> 6;
  const __hip_bfloat16* yb = y + (size_t)n4 * 1048576 + h * 64 + w;
  float v[64];
  float s1 = 0.f, s2 = 0.f;
  #pragma unroll
  for (int i = 0; i < 64; ++i) {
    v[i] = __bfloat162float(yb[(size_t)(cq * 64 + i) * 4096]);
    s1 += v[i];
    s2 = fmaf(v[i], v[i], s2);
  }
  ps[cq][w] = s1; pq[cq][w] = s2;
  __syncthreads();
  if (t < 64) {
    float a = ps[0][t] + ps[1][t] + ps[2][t] + ps[3][t];
    float b = pq[0][t] + pq[1][t] + pq[2][t] + pq[3][t];
    float mu = a * (1.f / 256.f);
    mu_s[t] = mu;
    rs_s[t] = rsqrtf(b * (1.f / 256.f) - mu * mu + 1e-5f);
  }
  __syncthreads();
  const float mu = mu_s[w], rs = rs_s[w];
  #pragma unroll
  for (int i = 0; i < 64; ++i) {
    int c = cq * 64 + i;
    float yv = fmaf((v[i] - mu) * rs, ln_g[c], ln_b[c]);
    float ge = 0.5f * yv * (1.f + erff(yv * 0.70710678f));
    st[c * 65 + w] = f2bf(ge);
  }
  __syncthreads();
  const size_t row0 = (size_t)n4 * 4096 + (size_t)h * 64;
  #pragma unroll
  for (int r = 0; r < 16; ++r) {
    int idx = t + r * 256;               // 4096 = 64 pix * 64 cquads
    int pix = idx >> 6, cq4 = idx & 63;
    unsigned short b0 = st[(cq4 * 4 + 0) * 65 + pix];
    unsigned short b1 = st[(cq4 * 4 + 1) * 65 + pix];
    unsigned short b2 = st[(cq4 * 4 + 2) * 65 + pix];
    unsigned short b3 = st[(cq4 * 4 + 3) * 65 + pix];
    uint2 u;
    u.x = (unsigned)b0 | ((unsigned)b1 << 16);
    u.y = (unsigned)b2 | ((unsigned)b3 << 16);
    *(uint2*)&x1[(row0 + pix) * 256 + cq4 * 4] = u;
  }
}

// ---------------- fused: deformable sampling + output GEMM + NCHW store -----
// block = 32 pixels; LDS: om tile (29184B) + samp tile (16896B) + Bs (16384B)
__global__ __launch_bounds__(256) void fused_out(
    const __hip_bfloat16* __restrict__ xpu, const __hip_bfloat16* __restrict__ om,
    const __hip_bfloat16* __restrict__ BtO, const float* __restrict__ out_b,
    float* __restrict__ out)
{
  __shared__ __align__(16) char smem[62464];
  unsigned short* oms = (unsigned short*)smem;     // 32 rows x 456 shorts
  short* sampS = (short*)(smem + 29184);           // 32 rows x 264 shorts
  short* BsS   = (short*)(smem + 46080);           // 256 x 32 shorts
  float* tb    = (float*)smem;                     // epilogue reuse: 32x33 fp32

  const int t = threadIdx.x;
  const int bid = blockIdx.x;
  const int region = bid & 7, qb = bid >> 3;       // XCD swizzle
  const int pix0 = region * 2048 + qb * 32;
  const int n4 = pix0 >> 12;
  const int hw0 = pix0 & 4095;

  {  // stage om: 32 rows x 56 uint4 -> padded rows of 57 uint4
    const uint4* gsrc = (const uint4*)(om + (size_t)pix0 * 448);
    uint4* dst = (uint4*)oms;
    #pragma unroll
    for (int k = 0; k < 7; ++k) {
      int i = t + k * 256;
      int row = i / 56, col = i - row * 56;
      dst[row * 57 + col] = gsrc[i];
    }
  }
  __syncthreads();

  #pragma unroll
  for (int pass = 0; pass < 2; ++pass) {
    int id = t + pass * 256;
    int g = id & 15, pl = id >> 4;                 // pl 0..31
    int hw = hw0 + pl;
    int h = hw >> 6, w = hw & 63;
    const unsigned short* ob = &oms[pl * 456];

    float mk[9];
    float mx = -1e30f;
    #pragma unroll
    for (int p = 0; p < 9; ++p) { mk[p] = us2f(ob[288 + g * 9 + p]); mx = fmaxf(mx, mk[p]); }
    float se = 0.f;
    #pragma unroll
    for (int p = 0; p < 9; ++p) { mk[p] = __expf(mk[p] - mx); se += mk[p]; }
    float inv = 1.f / se;

    const __hip_bfloat16* xpg = xpu + (g << 4);
    float ax[16];
    #pragma unroll
    for (int i = 0; i < 16; ++i) ax[i] = 0.f;

    auto corner = [&](int iy, int ix, float wt) {
      if ((unsigned)(iy - 1) >= 64u || (unsigned)(ix - 1) >= 64u) return;
      const __hip_bfloat16* src =
          xpg + ((size_t)((n4 << 12) + (iy - 1) * 64 + (ix - 1)) << 8);
      uint4 u0 = *(const uint4*)src;
      uint4 u1 = *(const uint4*)(src + 8);
      const unsigned uu[8] = {u0.x, u0.y, u0.z, u0.w, u1.x, u1.y, u1.z, u1.w};
      #pragma unroll
      for (int i = 0; i < 8; ++i) {
        float lo = us2f((unsigned short)(uu[i] & 0xffff));
        float hi = us2f((unsigned short)(uu[i] >> 16));
        ax[2 * i + 0] = fmaf(wt, lo, ax[2 * i + 0]);
        ax[2 * i + 1] = fmaf(wt, hi, ax[2 * i + 1]);
      }
    };

    #pragma unroll
    for (int p = 0; p < 9; ++p) {
      float ox = us2f(ob[2 * (g * 9 + p)]), oy = us2f(ob[2 * (g * 9 + p) + 1]);
      float px = (float)(w + p / 3) + ox;
      float py = (float)(h + p % 3) + oy;
      float xf = floorf(px), yf = floorf(py);
      float wx = px - xf, wy = py - yf;
      int ix = (int)xf, iy = (int)yf;
      float m = mk[p] * inv;
      corner(iy,     ix,     (1.f - wy) * (1.f - wx) * m);
      corner(iy,     ix + 1, (1.f - wy) * wx * m);
      corner(iy + 1, ix,     wy * (1.f - wx) * m);
      corner(iy + 1, ix + 1, wy * wx * m);
    }

    unsigned short ub[16];
    #pragma unroll
    for (int i = 0; i < 16; ++i) ub[i] = f2bf(ax[i]);
    uint4 u0, u1;
    u0.x = (unsigned)ub[0] | ((unsigned)ub[1] << 16);
    u0.y = (unsigned)ub[2] | ((unsigned)ub[3] << 16);
    u0.z = (unsigned)ub[4] | ((unsigned)ub[5] << 16);
    u0.w = (unsigned)ub[6] | ((unsigned)ub[7] << 16);
    u1.x = (unsigned)ub[8] | ((unsigned)ub[9] << 16);
    u1.y = (unsigned)ub[10] | ((unsigned)ub[11] << 16);
    u1.z = (unsigned)ub[12] | ((unsigned)ub[13] << 16);
    u1.w = (unsigned)ub[14] | ((unsigned)ub[15] << 16);
    *(uint4*)&sampS[pl * 264 + g * 16] = u0;
    *(uint4*)&sampS[pl * 264 + g * 16 + 8] = u1;
  }
  __syncthreads();

  // GEMM: 32m x 256n, K=256. 4 waves, wave = n-quadrant of 64 cols.
  const int wave = t >> 6, lane = t & 63;
  const int quad = lane >> 4, lr = lane & 15;
  f32x4 acc[2][4];
  #pragma unroll
  for (int i = 0; i < 2; ++i)
    #pragma unroll
    for (int j = 0; j < 4; ++j)
      acc[i][j] = (f32x4){0.f, 0.f, 0.f, 0.f};

  for (int kt = 0; kt < 256; kt += 32) {
    #pragma unroll
    for (int j = 0; j < 4; ++j) {
      int row = wave * 64 + j * 16 + (lane >> 2), kq = lane & 3;
      g2lds16(BtO + (size_t)row * 256 + kt + kq * 8,
              (char*)BsS + wave * 4096 + j * 1024 + lane * 16);
    }
    __syncthreads();
    bf16x8 bfv[4];
    #pragma unroll
    for (int ni = 0; ni < 4; ++ni)
      bfv[ni] = *(const bf16x8*)&BsS[(wave * 64 + ni * 16 + lr) * 32 + quad * 8];
    #pragma unroll
    for (int mi = 0; mi < 2; ++mi) {
      bf16x8 af = *(const bf16x8*)&sampS[(mi * 16 + lr) * 264 + kt + quad * 8];
      #pragma unroll
      for (int ni = 0; ni < 4; ++ni)
        acc[mi][ni] = __builtin_amdgcn_mfma_f32_16x16x32_bf16(af, bfv[ni], acc[mi][ni], 0, 0, 0);
    }
    __syncthreads();
  }

  // epilogue: per 32-col chunk, LDS transpose -> NCHW float4 stores
  for (int qc = 0; qc < 8; ++qc) {
    __syncthreads();
    if (wave == (qc >> 1)) {
      #pragma unroll
      for (int s = 0; s < 2; ++s) {
        int ni = (qc & 1) * 2 + s;
        int col = wave * 64 + ni * 16 + lr;
        float bv = out_b[col];
        int cl = s * 16 + lr;
        #pragma unroll
        for (int mi = 0; mi < 2; ++mi)
          #pragma unroll
          for (int reg = 0; reg < 4; ++reg)
            tb[cl * 33 + mi * 16 + quad * 4 + reg] = acc[mi][ni][reg] + bv;
      }
    }
    __syncthreads();
    int row = t >> 3, mc = (t & 7) * 4;
    int co = qc * 32 + row;
    float4 v;
    v.x = tb[row * 33 + mc + 0];
    v.y = tb[row * 33 + mc + 1];
    v.z = tb[row * 33 + mc + 2];
    v.w = tb[row * 33 + mc + 3];
    *(float4*)&out[(size_t)(n4 * 256 + co) * 4096 + hw0 + mc] = v;
  }
}

extern "C" void kernel_launch(void* const* d_in, const int* in_sizes, int n_in,
                              void* d_out, int out_size, void* d_ws, size_t ws_size,
                              hipStream_t stream) {
  const float* x      = (const float*)d_in[0];
  const float* dw_w   = (const float*)d_in[1];
  const float* dw_b   = (const float*)d_in[2];
  const float* ln_g   = (const float*)d_in[3];
  const float* ln_b   = (const float*)d_in[4];
  const float* off_w  = (const float*)d_in[5];
  const float* off_b  = (const float*)d_in[6];
  const float* mask_w = (const float*)d_in[7];
  const float* mask_b = (const float*)d_in[8];
  const float* inp_w  = (const float*)d_in[9];
  const float* inp_b  = (const float*)d_in[10];
  const float* out_w  = (const float*)d_in[11];
  const float* out_b  = (const float*)d_in[12];
  float* out = (float*)d_out;

  char* w0 = (char*)d_ws;
  __hip_bfloat16* xpu  = (__hip_bfloat16*)(w0);               //  8,388,608 B
  __hip_bfloat16* y    = (__hip_bfloat16*)(w0 + 8388608);     //  8,388,608 B
  __hip_bfloat16* x1   = (__hip_bfloat16*)(w0 + 16777216);    //  8,388,608 B
  __hip_bfloat16* om   = (__hip_bfloat16*)(w0 + 25165824);    // 14,680,064 B
  __hip_bfloat16* BtI  = (__hip_bfloat16*)(w0 + 39845888);    //    131,072 B
  __hip_bfloat16* BtOM = (__hip_bfloat16*)(w0 + 39976960);    //    262,144 B
  __hip_bfloat16* BtO  = (__hip_bfloat16*)(w0 + 40239104);    //    131,072 B
  float*          bOM  = (float*)(w0 + 40370176);             //      2,048 B
  if (ws_size < 40372224) return;

  prep_k<<<1024, 256, 0, stream>>>(inp_w, off_w, off_b, mask_w, mask_b, out_w,
                                   BtI, BtOM, BtO, bOM);
  gemm_mfma<1><<<dim3(2, 128), 256, 0, stream>>>(x, BtI, inp_b, xpu, 256, 256);
  dwconv_k<<<1024, 256, 0, stream>>>(x, dw_w, dw_b, y);
  ln_k<<<256, 256, 0, stream>>>(y, ln_g, ln_b, x1);
  gemm_mfma<0><<<dim3(4, 128), 256, 0, stream>>>(x1, BtOM, bOM, om, 448, 432);
  fused_out<<<512, 256, 0, stream>>>(xpu, om, BtO, out_b, out);
}

// Round 5
// 184.106 us; speedup vs baseline: 1.0908x; 1.0908x over previous
//
#include <hip/hip_runtime.h>
#include <hip/hip_bf16.h>
#include <math.h>

// R5: R3 structure (split sampler) + coalesced ln_k v2 + bf16 y. 8 dispatches.

using bf16x8 = __attribute__((ext_vector_type(8))) short;
using f32x4  = __attribute__((ext_vector_type(4))) float;

#define GLOBAL_AS __attribute__((address_space(1)))
#define LDS_AS    __attribute__((address_space(3)))

static __device__ inline void g2lds16(const void* g, void* l) {
  __builtin_amdgcn_global_load_lds((const GLOBAL_AS int*)g, (LDS_AS int*)l, 16, 0, 0);
}
static __device__ inline unsigned short f2bf(float v) {
  __hip_bfloat16 b = __float2bfloat16(v);
  return *reinterpret_cast<unsigned short*>(&b);
}
static __device__ inline float us2f(unsigned short u) {
  union { unsigned u; float f; } c; c.u = ((unsigned)u) << 16; return c.f;
}

// ---------------- weight prep: W[k][n] fp32 -> Bt[n][k] bf16 (+pad) ---------
__global__ __launch_bounds__(256) void prep_k(
    const float* __restrict__ inp_w, const float* __restrict__ off_w,
    const float* __restrict__ off_b, const float* __restrict__ mask_w,
    const float* __restrict__ mask_b, const float* __restrict__ out_w,
    __hip_bfloat16* __restrict__ BtI, __hip_bfloat16* __restrict__ BtOM,
    __hip_bfloat16* __restrict__ BtO, float* __restrict__ bOM)
{
  int b = blockIdx.x, t = threadIdx.x;   // t = k index
  if (b < 256) {
    int n = b;
    BtI[n * 256 + t] = __float2bfloat16(inp_w[t * 256 + n]);
  } else if (b < 768) {
    int n = b - 256;
    float v = 0.f;
    if (n < 288) v = off_w[t * 288 + n];
    else if (n < 432) v = mask_w[t * 144 + (n - 288)];
    BtOM[n * 256 + t] = __float2bfloat16(v);
    if (b == 256) {
      for (int idx = t; idx < 512; idx += 256) {
        float bv = (idx < 288) ? off_b[idx] : ((idx < 432) ? mask_b[idx - 288] : 0.f);
        bOM[idx] = bv;
      }
    }
  } else {
    int n = b - 768;
    BtO[n * 256 + t] = __float2bfloat16(out_w[t * 256 + n]);
  }
}

// ---------------- x NCHW fp32 -> xT [pix][c] bf16 ---------------------------
__global__ __launch_bounds__(256) void xt_k(const float* __restrict__ x,
                                            __hip_bfloat16* __restrict__ xT) {
  __shared__ float tile[32][65];
  const int hw0 = blockIdx.x * 64, c0 = blockIdx.y * 32, n4 = blockIdx.z;
  const int t = threadIdx.x;
  #pragma unroll
  for (int r = 0; r < 8; ++r) {
    int idx = t + r * 256;
    int cl = idx >> 6, wl = idx & 63;
    tile[cl][wl] = x[(size_t)n4 * 1048576 + (size_t)(c0 + cl) * 4096 + hw0 + wl];
  }
  __syncthreads();
  #pragma unroll
  for (int r = 0; r < 2; ++r) {
    int idx = t + r * 256;           // 512 tasks = 64 pix * 8 cquads
    int pixl = idx >> 3, cq = idx & 7;
    unsigned short b0 = f2bf(tile[cq * 4 + 0][pixl]);
    unsigned short b1 = f2bf(tile[cq * 4 + 1][pixl]);
    unsigned short b2 = f2bf(tile[cq * 4 + 2][pixl]);
    unsigned short b3 = f2bf(tile[cq * 4 + 3][pixl]);
    uint2 u;
    u.x = (unsigned)b0 | ((unsigned)b1 << 16);
    u.y = (unsigned)b2 | ((unsigned)b3 << 16);
    *(uint2*)&xT[((size_t)n4 * 4096 + hw0 + pixl) * 256 + c0 + cq * 4] = u;
  }
}

// ---------------- MFMA GEMM: C[16384 x N] = A[16384 x 256] * Bt^T + bias ----
// A bf16 [m][256], Bt bf16 [n][256]. 128x128 tile, BK=32, 4 waves 2x2.
// CMODE 2: bf16 row-major C (ldc, nstore). CMODE 3: fp32 NCHW out.
template<int CMODE>
__global__ __launch_bounds__(256) void gemm_mfma(
    const __hip_bfloat16* __restrict__ A, const __hip_bfloat16* __restrict__ Bt,
    const float* __restrict__ bias, void* __restrict__ Cv, int ldc, int nstore)
{
  __shared__ __align__(16) char smem[16512];
  short* As = (short*)smem;            // [128][32] bf16 = 8192 B
  short* Bs = (short*)(smem + 8192);   // [128][32] bf16 = 8192 B
  float* tb = (float*)smem;            // CMODE 3 epilogue: [32][129]
  const int t = threadIdx.x;
  const int wave = t >> 6, lane = t & 63;
  const int quad = lane >> 4, lr = lane & 15;
  const int wm = wave >> 1, wn = wave & 1;
  const size_t m0 = (size_t)blockIdx.y * 128;
  const int n0 = blockIdx.x * 128;

  f32x4 acc[4][4];
  #pragma unroll
  for (int i = 0; i < 4; ++i)
    #pragma unroll
    for (int j = 0; j < 4; ++j)
      acc[i][j] = (f32x4){0.f, 0.f, 0.f, 0.f};

  const int srow = wave * 32;
  for (int kt = 0; kt < 256; kt += 32) {
    #pragma unroll
    for (int j = 0; j < 2; ++j) {
      int chunk = j * 64 + lane;
      int row = srow + (chunk >> 2), kq = chunk & 3;
      const __hip_bfloat16* gA = A + (m0 + row) * 256 + kt + kq * 8;
      const __hip_bfloat16* gB = Bt + (size_t)(n0 + row) * 256 + kt + kq * 8;
      g2lds16(gA, (char*)As + wave * 2048 + j * 1024);
      g2lds16(gB, (char*)Bs + wave * 2048 + j * 1024);
    }
    __syncthreads();
    bf16x8 bfv[4];
    #pragma unroll
    for (int ni = 0; ni < 4; ++ni)
      bfv[ni] = *(const bf16x8*)&Bs[(wn * 64 + ni * 16 + lr) * 32 + quad * 8];
    #pragma unroll
    for (int mi = 0; mi < 4; ++mi) {
      bf16x8 af = *(const bf16x8*)&As[(wm * 64 + mi * 16 + lr) * 32 + quad * 8];
      #pragma unroll
      for (int ni = 0; ni < 4; ++ni)
        acc[mi][ni] = __builtin_amdgcn_mfma_f32_16x16x32_bf16(af, bfv[ni], acc[mi][ni], 0, 0, 0);
    }
    __syncthreads();
  }

  if (CMODE == 2) {
    #pragma unroll
    for (int mi = 0; mi < 4; ++mi) {
      #pragma unroll
      for (int ni = 0; ni < 4; ++ni) {
        int col = n0 + wn * 64 + ni * 16 + lr;
        if (col < nstore) {
          float bv = bias[col];
          #pragma unroll
          for (int reg = 0; reg < 4; ++reg) {
            size_t m = m0 + wm * 64 + mi * 16 + quad * 4 + reg;
            ((__hip_bfloat16*)Cv)[m * ldc + col] =
                __float2bfloat16(acc[mi][ni][reg] + bv);
          }
        }
      }
    }
  } else {
    const int n4 = (int)(m0 >> 12), hw0 = (int)(m0 & 4095);
    for (int qc = 0; qc < 4; ++qc) {
      __syncthreads();
      if (wn == (qc >> 1)) {
        #pragma unroll
        for (int nis = 0; nis < 2; ++nis) {
          int ni = 2 * (qc & 1) + nis;
          int col = n0 + wn * 64 + ni * 16 + lr;
          float bv = bias[col];
          int cl = nis * 16 + lr;
          #pragma unroll
          for (int mi = 0; mi < 4; ++mi)
            #pragma unroll
            for (int reg = 0; reg < 4; ++reg) {
              int ml = wm * 64 + mi * 16 + quad * 4 + reg;
              tb[cl * 129 + ml] = acc[mi][ni][reg] + bv;
            }
        }
      }
      __syncthreads();
      #pragma unroll
      for (int r = 0; r < 4; ++r) {
        int f4i = t + r * 256;
        int row = f4i >> 5, mc = (f4i & 31) * 4;
        int co = n0 + qc * 32 + row;
        float4 v;
        v.x = tb[row * 129 + mc + 0];
        v.y = tb[row * 129 + mc + 1];
        v.z = tb[row * 129 + mc + 2];
        v.w = tb[row * 129 + mc + 3];
        *(float4*)&((float*)Cv)[(size_t)(n4 * 256 + co) * 4096 + hw0 + mc] = v;
      }
    }
  }
}

// ---------------- depthwise 3x3: block per (n,c) plane, fp32 x -> bf16 y ----
__global__ __launch_bounds__(256) void dwconv_k(
    const float* __restrict__ x, const float* __restrict__ dw_w,
    const float* __restrict__ dw_b, __hip_bfloat16* __restrict__ y)
{
  __shared__ float pl[4096];            // 64x64 plane
  const int bc = blockIdx.x;
  const int n4 = bc >> 8, c = bc & 255;
  const int t = threadIdx.x;
  const float* xc = x + (size_t)n4 * 1048576 + (size_t)c * 4096;
  #pragma unroll
  for (int r = 0; r < 4; ++r) {
    int idx4 = t + r * 256;
    *(float4*)&pl[idx4 * 4] = *(const float4*)&xc[idx4 * 4];
  }
  float wv[9];
  #pragma unroll
  for (int i = 0; i < 9; ++i) wv[i] = dw_w[c * 9 + i];
  const float bb = dw_b[c];
  __syncthreads();
  __hip_bfloat16* yc = y + (size_t)(n4 * 256 + c) * 4096;
  #pragma unroll 4
  for (int r = 0; r < 16; ++r) {
    int px = t + r * 256;
    int h = px >> 6, w = px & 63;
    float s = bb;
    #pragma unroll
    for (int dh = -1; dh <= 1; ++dh) {
      int hh = h + dh;
      if ((unsigned)hh >= 64u) continue;
      #pragma unroll
      for (int dw = -1; dw <= 1; ++dw) {
        int ww = w + dw;
        if ((unsigned)ww >= 64u) continue;
        s = fmaf(pl[hh * 64 + ww], wv[(dh + 1) * 3 + (dw + 1)], s);
      }
    }
    yc[px] = __float2bfloat16(s);
  }
}

// ---------------- LayerNorm(C) + GELU v2: coalesced staged loads ------------
// block = one image row (64 px). y bf16 NCHW -> x1 bf16 [pix][c].
__global__ __launch_bounds__(256) void ln_k(
    const __hip_bfloat16* __restrict__ y, const float* __restrict__ ln_g,
    const float* __restrict__ ln_b, __hip_bfloat16* __restrict__ x1)
{
  __shared__ unsigned short ys[256 * 66];       // 33792 B, stride 66: conflict-lite
  __shared__ float gs[256], bs2[256];
  __shared__ float ps[4][64], pq[4][64], mu_s[64], rs_s[64];
  const int blk = blockIdx.x;                   // n4*64 + h
  const int n4 = blk >> 6, h = blk & 63;
  const int t = threadIdx.x;

  gs[t] = ln_g[t]; bs2[t] = ln_b[t];

  // phase 1: coalesced uint4 loads (8 bf16 along w) -> ys[c][w]
  const __hip_bfloat16* yb = y + (size_t)n4 * 1048576 + h * 64;
  #pragma unroll
  for (int r = 0; r < 8; ++r) {
    int idx = t + r * 256;            // 2048 tasks: c = idx>>3, w8 = idx&7
    int c = idx >> 3, w8 = idx & 7;
    uint4 u = *(const uint4*)(yb + (size_t)c * 4096 + w8 * 8);
    unsigned* d = (unsigned*)&ys[c * 66 + w8 * 8];
    d[0] = u.x; d[1] = u.y; d[2] = u.z; d[3] = u.w;
  }
  __syncthreads();

  // phase 2: per-pixel sums over channels
  const int w = t & 63, q = t >> 6;
  {
    float s1 = 0.f, s2 = 0.f;
    #pragma unroll
    for (int i = 0; i < 64; ++i) {
      float v = us2f(ys[(q * 64 + i) * 66 + w]);
      s1 += v; s2 = fmaf(v, v, s2);
    }
    ps[q][w] = s1; pq[q][w] = s2;
  }
  __syncthreads();
  if (t < 64) {
    float a = ps[0][t] + ps[1][t] + ps[2][t] + ps[3][t];
    float b = pq[0][t] + pq[1][t] + pq[2][t] + pq[3][t];
    float mu = a * (1.f / 256.f);
    mu_s[t] = mu;
    rs_s[t] = rsqrtf(b * (1.f / 256.f) - mu * mu + 1e-5f);
  }
  __syncthreads();

  // phase 3: normalize + GELU in place (thread owns (c-range, w))
  const float mu = mu_s[w], rs = rs_s[w];
  #pragma unroll
  for (int i = 0; i < 64; ++i) {
    int c = q * 64 + i;
    float v = us2f(ys[c * 66 + w]);
    float yv = fmaf((v - mu) * rs, gs[c], bs2[c]);
    float ge = 0.5f * yv * (1.f + erff(yv * 0.70710678f));
    ys[c * 66 + w] = f2bf(ge);
  }
  __syncthreads();

  // phase 4: transposed coalesced stores to x1 [pix][c]
  const size_t row0 = ((size_t)n4 * 4096 + (size_t)h * 64) * 256;
  #pragma unroll
  for (int r = 0; r < 8; ++r) {
    int idx = t + r * 256;            // 2048: pix = idx>>5, co8 = idx&31
    int pix = idx >> 5, co8 = idx & 31;
    unsigned short v0 = ys[(co8 * 8 + 0) * 66 + pix];
    unsigned short v1 = ys[(co8 * 8 + 1) * 66 + pix];
    unsigned short v2 = ys[(co8 * 8 + 2) * 66 + pix];
    unsigned short v3 = ys[(co8 * 8 + 3) * 66 + pix];
    unsigned short v4 = ys[(co8 * 8 + 4) * 66 + pix];
    unsigned short v5 = ys[(co8 * 8 + 5) * 66 + pix];
    unsigned short v6 = ys[(co8 * 8 + 6) * 66 + pix];
    unsigned short v7 = ys[(co8 * 8 + 7) * 66 + pix];
    uint4 u;
    u.x = (unsigned)v0 | ((unsigned)v1 << 16);
    u.y = (unsigned)v2 | ((unsigned)v3 << 16);
    u.z = (unsigned)v4 | ((unsigned)v5 << 16);
    u.w = (unsigned)v6 | ((unsigned)v7 << 16);
    *(uint4*)&x1[row0 + (size_t)pix * 256 + co8 * 8] = u;
  }
}

// ---------------- deformable sampling (swizzled; bf16 xpu; om via LDS) ------
__global__ __launch_bounds__(256) void sample_k(
    const __hip_bfloat16* __restrict__ xpu, const __hip_bfloat16* __restrict__ om,
    __hip_bfloat16* __restrict__ samp)
{
  __shared__ unsigned short oms[16 * 448];   // 14336 B
  const int bid = blockIdx.x;                // 1024
  const int region = bid & 7;                // XCD under round-robin dispatch
  const int q = bid >> 3;                    // 0..127 within region
  const int pix0 = region * 2048 + q * 16;   // 16 consecutive pixels
  const int t = threadIdx.x;

  {  // stage om tile: 16 px * 448 bf16 = 896 uint4
    const uint4* gsrc = (const uint4*)(om + (size_t)pix0 * 448);
    uint4* ldst = (uint4*)oms;
    #pragma unroll
    for (int r = 0; r < 4; ++r) {
      int i = t + r * 256;
      if (i < 896) ldst[i] = gsrc[i];
    }
  }
  __syncthreads();

  const int g = t & 15;
  const int pl = t >> 4;
  const int pix = pix0 + pl;
  const int n4 = pix >> 12;
  const int hw = pix & 4095;
  const int h = hw >> 6, w = hw & 63;

  float mk[9];
  {
    const unsigned short* mp = &oms[pl * 448 + 288 + g * 9];
    float mx = -1e30f;
    #pragma unroll
    for (int p = 0; p < 9; ++p) { mk[p] = us2f(mp[p]); mx = fmaxf(mx, mk[p]); }
    float se = 0.f;
    #pragma unroll
    for (int p = 0; p < 9; ++p) { mk[p] = __expf(mk[p] - mx); se += mk[p]; }
    float inv = 1.f / se;
    #pragma unroll
    for (int p = 0; p < 9; ++p) mk[p] *= inv;
  }

  const unsigned short* op = &oms[pl * 448 + g * 18];
  const __hip_bfloat16* xpg = xpu + (g << 4);
  float ax[16];
  #pragma unroll
  for (int i = 0; i < 16; ++i) ax[i] = 0.f;

  auto corner = [&](int iy, int ix, float wt) {
    // padded coords: data nonzero iff 1<=iy<=64 && 1<=ix<=64
    if ((unsigned)(iy - 1) >= 64u || (unsigned)(ix - 1) >= 64u) return;
    const __hip_bfloat16* src =
        xpg + ((size_t)((n4 << 12) + (iy - 1) * 64 + (ix - 1)) << 8);
    uint4 u0 = *(const uint4*)src;
    uint4 u1 = *(const uint4*)(src + 8);
    const unsigned uu[8] = {u0.x, u0.y, u0.z, u0.w, u1.x, u1.y, u1.z, u1.w};
    #pragma unroll
    for (int i = 0; i < 8; ++i) {
      float lo = us2f((unsigned short)(uu[i] & 0xffff));
      float hi = us2f((unsigned short)(uu[i] >> 16));
      ax[2 * i + 0] = fmaf(wt, lo, ax[2 * i + 0]);
      ax[2 * i + 1] = fmaf(wt, hi, ax[2 * i + 1]);
    }
  };

  #pragma unroll
  for (int p = 0; p < 9; ++p) {
    float ox = us2f(op[2 * p]), oy = us2f(op[2 * p + 1]);
    float px = (float)(w + p / 3) + ox;    // padded-space coords
    float py = (float)(h + p % 3) + oy;
    float xf = floorf(px), yf = floorf(py);
    float wx = px - xf, wy = py - yf;
    int ix = (int)xf, iy = (int)yf;
    float m = mk[p];
    corner(iy,     ix,     (1.f - wy) * (1.f - wx) * m);
    corner(iy,     ix + 1, (1.f - wy) * wx * m);
    corner(iy + 1, ix,     wy * (1.f - wx) * m);
    corner(iy + 1, ix + 1, wy * wx * m);
  }

  unsigned short ub[16];
  #pragma unroll
  for (int i = 0; i < 16; ++i) ub[i] = f2bf(ax[i]);
  uint4* d4 = (uint4*)(samp + (size_t)pix * 256 + (g << 4));
  uint4 u0, u1;
  u0.x = (unsigned)ub[0] | ((unsigned)ub[1] << 16);
  u0.y = (unsigned)ub[2] | ((unsigned)ub[3] << 16);
  u0.z = (unsigned)ub[4] | ((unsigned)ub[5] << 16);
  u0.w = (unsigned)ub[6] | ((unsigned)ub[7] << 16);
  u1.x = (unsigned)ub[8] | ((unsigned)ub[9] << 16);
  u1.y = (unsigned)ub[10] | ((unsigned)ub[11] << 16);
  u1.z = (unsigned)ub[12] | ((unsigned)ub[13] << 16);
  u1.w = (unsigned)ub[14] | ((unsigned)ub[15] << 16);
  d4[0] = u0; d4[1] = u1;
}

extern "C" void kernel_launch(void* const* d_in, const int* in_sizes, int n_in,
                              void* d_out, int out_size, void* d_ws, size_t ws_size,
                              hipStream_t stream) {
  const float* x      = (const float*)d_in[0];
  const float* dw_w   = (const float*)d_in[1];
  const float* dw_b   = (const float*)d_in[2];
  const float* ln_g   = (const float*)d_in[3];
  const float* ln_b   = (const float*)d_in[4];
  const float* off_w  = (const float*)d_in[5];
  const float* off_b  = (const float*)d_in[6];
  const float* mask_w = (const float*)d_in[7];
  const float* mask_b = (const float*)d_in[8];
  const float* inp_w  = (const float*)d_in[9];
  const float* inp_b  = (const float*)d_in[10];
  const float* out_w  = (const float*)d_in[11];
  const float* out_b  = (const float*)d_in[12];
  float* out = (float*)d_out;

  char* w0 = (char*)d_ws;
  __hip_bfloat16* xpu  = (__hip_bfloat16*)(w0);               //  8,388,608 B
  __hip_bfloat16* y    = (__hip_bfloat16*)(w0 + 8388608);     //  8,388,608 B
  __hip_bfloat16* x1   = (__hip_bfloat16*)(w0 + 16777216);    //  8,388,608 B
  __hip_bfloat16* xT   = (__hip_bfloat16*)(w0 + 25165824);    //  8,388,608 B
  __hip_bfloat16* samp = xT;                                  // alias (xT dead)
  __hip_bfloat16* om   = (__hip_bfloat16*)(w0 + 33554432);    // 14,680,064 B
  __hip_bfloat16* BtI  = (__hip_bfloat16*)(w0 + 48234496);    //    131,072 B
  __hip_bfloat16* BtOM = (__hip_bfloat16*)(w0 + 48365568);    //    262,144 B
  __hip_bfloat16* BtO  = (__hip_bfloat16*)(w0 + 48627712);    //    131,072 B
  float*          bOM  = (float*)(w0 + 48758784);             //      2,048 B
  if (ws_size < 48760832) return;

  prep_k<<<1024, 256, 0, stream>>>(inp_w, off_w, off_b, mask_w, mask_b, out_w,
                                   BtI, BtOM, BtO, bOM);
  xt_k<<<dim3(64, 8, 4), 256, 0, stream>>>(x, xT);
  gemm_mfma<2><<<dim3(2, 128), 256, 0, stream>>>(xT, BtI, inp_b, xpu, 256, 256);
  dwconv_k<<<1024, 256, 0, stream>>>(x, dw_w, dw_b, y);
  ln_k<<<256, 256, 0, stream>>>(y, ln_g, ln_b, x1);
  gemm_mfma<2><<<dim3(4, 128), 256, 0, stream>>>(x1, BtOM, bOM, om, 448, 432);
  sample_k<<<1024, 256, 0, stream>>>(xpu, om, samp);
  gemm_mfma<3><<<dim3(2, 128), 256, 0, stream>>>(samp, BtO, out_b, out, 0, 256);
}

// Round 6
// 173.046 us; speedup vs baseline: 1.1606x; 1.0639x over previous
//
#include <hip/hip_runtime.h>
#include <hip/hip_bf16.h>
#include <math.h>

// R6: ln_k v3 (1024 threads/block — fix 1-wave/SIMD latency exposure).
// Rest identical to R5. 8 dispatches.

using bf16x8 = __attribute__((ext_vector_type(8))) short;
using f32x4  = __attribute__((ext_vector_type(4))) float;

#define GLOBAL_AS __attribute__((address_space(1)))
#define LDS_AS    __attribute__((address_space(3)))

static __device__ inline void g2lds16(const void* g, void* l) {
  __builtin_amdgcn_global_load_lds((const GLOBAL_AS int*)g, (LDS_AS int*)l, 16, 0, 0);
}
static __device__ inline unsigned short f2bf(float v) {
  __hip_bfloat16 b = __float2bfloat16(v);
  return *reinterpret_cast<unsigned short*>(&b);
}
static __device__ inline float us2f(unsigned short u) {
  union { unsigned u; float f; } c; c.u = ((unsigned)u) << 16; return c.f;
}

// ---------------- weight prep: W[k][n] fp32 -> Bt[n][k] bf16 (+pad) ---------
__global__ __launch_bounds__(256) void prep_k(
    const float* __restrict__ inp_w, const float* __restrict__ off_w,
    const float* __restrict__ off_b, const float* __restrict__ mask_w,
    const float* __restrict__ mask_b, const float* __restrict__ out_w,
    __hip_bfloat16* __restrict__ BtI, __hip_bfloat16* __restrict__ BtOM,
    __hip_bfloat16* __restrict__ BtO, float* __restrict__ bOM)
{
  int b = blockIdx.x, t = threadIdx.x;   // t = k index
  if (b < 256) {
    int n = b;
    BtI[n * 256 + t] = __float2bfloat16(inp_w[t * 256 + n]);
  } else if (b < 768) {
    int n = b - 256;
    float v = 0.f;
    if (n < 288) v = off_w[t * 288 + n];
    else if (n < 432) v = mask_w[t * 144 + (n - 288)];
    BtOM[n * 256 + t] = __float2bfloat16(v);
    if (b == 256) {
      for (int idx = t; idx < 512; idx += 256) {
        float bv = (idx < 288) ? off_b[idx] : ((idx < 432) ? mask_b[idx - 288] : 0.f);
        bOM[idx] = bv;
      }
    }
  } else {
    int n = b - 768;
    BtO[n * 256 + t] = __float2bfloat16(out_w[t * 256 + n]);
  }
}

// ---------------- x NCHW fp32 -> xT [pix][c] bf16 ---------------------------
__global__ __launch_bounds__(256) void xt_k(const float* __restrict__ x,
                                            __hip_bfloat16* __restrict__ xT) {
  __shared__ float tile[32][65];
  const int hw0 = blockIdx.x * 64, c0 = blockIdx.y * 32, n4 = blockIdx.z;
  const int t = threadIdx.x;
  #pragma unroll
  for (int r = 0; r < 8; ++r) {
    int idx = t + r * 256;
    int cl = idx >> 6, wl = idx & 63;
    tile[cl][wl] = x[(size_t)n4 * 1048576 + (size_t)(c0 + cl) * 4096 + hw0 + wl];
  }
  __syncthreads();
  #pragma unroll
  for (int r = 0; r < 2; ++r) {
    int idx = t + r * 256;           // 512 tasks = 64 pix * 8 cquads
    int pixl = idx >> 3, cq = idx & 7;
    unsigned short b0 = f2bf(tile[cq * 4 + 0][pixl]);
    unsigned short b1 = f2bf(tile[cq * 4 + 1][pixl]);
    unsigned short b2 = f2bf(tile[cq * 4 + 2][pixl]);
    unsigned short b3 = f2bf(tile[cq * 4 + 3][pixl]);
    uint2 u;
    u.x = (unsigned)b0 | ((unsigned)b1 << 16);
    u.y = (unsigned)b2 | ((unsigned)b3 << 16);
    *(uint2*)&xT[((size_t)n4 * 4096 + hw0 + pixl) * 256 + c0 + cq * 4] = u;
  }
}

// ---------------- MFMA GEMM: C[16384 x N] = A[16384 x 256] * Bt^T + bias ----
// CMODE 2: bf16 row-major C (ldc, nstore). CMODE 3: fp32 NCHW out.
template<int CMODE>
__global__ __launch_bounds__(256) void gemm_mfma(
    const __hip_bfloat16* __restrict__ A, const __hip_bfloat16* __restrict__ Bt,
    const float* __restrict__ bias, void* __restrict__ Cv, int ldc, int nstore)
{
  __shared__ __align__(16) char smem[16512];
  short* As = (short*)smem;            // [128][32] bf16 = 8192 B
  short* Bs = (short*)(smem + 8192);   // [128][32] bf16 = 8192 B
  float* tb = (float*)smem;            // CMODE 3 epilogue: [32][129]
  const int t = threadIdx.x;
  const int wave = t >> 6, lane = t & 63;
  const int quad = lane >> 4, lr = lane & 15;
  const int wm = wave >> 1, wn = wave & 1;
  const size_t m0 = (size_t)blockIdx.y * 128;
  const int n0 = blockIdx.x * 128;

  f32x4 acc[4][4];
  #pragma unroll
  for (int i = 0; i < 4; ++i)
    #pragma unroll
    for (int j = 0; j < 4; ++j)
      acc[i][j] = (f32x4){0.f, 0.f, 0.f, 0.f};

  const int srow = wave * 32;
  for (int kt = 0; kt < 256; kt += 32) {
    #pragma unroll
    for (int j = 0; j < 2; ++j) {
      int chunk = j * 64 + lane;
      int row = srow + (chunk >> 2), kq = chunk & 3;
      const __hip_bfloat16* gA = A + (m0 + row) * 256 + kt + kq * 8;
      const __hip_bfloat16* gB = Bt + (size_t)(n0 + row) * 256 + kt + kq * 8;
      g2lds16(gA, (char*)As + wave * 2048 + j * 1024);
      g2lds16(gB, (char*)Bs + wave * 2048 + j * 1024);
    }
    __syncthreads();
    bf16x8 bfv[4];
    #pragma unroll
    for (int ni = 0; ni < 4; ++ni)
      bfv[ni] = *(const bf16x8*)&Bs[(wn * 64 + ni * 16 + lr) * 32 + quad * 8];
    #pragma unroll
    for (int mi = 0; mi < 4; ++mi) {
      bf16x8 af = *(const bf16x8*)&As[(wm * 64 + mi * 16 + lr) * 32 + quad * 8];
      #pragma unroll
      for (int ni = 0; ni < 4; ++ni)
        acc[mi][ni] = __builtin_amdgcn_mfma_f32_16x16x32_bf16(af, bfv[ni], acc[mi][ni], 0, 0, 0);
    }
    __syncthreads();
  }

  if (CMODE == 2) {
    #pragma unroll
    for (int mi = 0; mi < 4; ++mi) {
      #pragma unroll
      for (int ni = 0; ni < 4; ++ni) {
        int col = n0 + wn * 64 + ni * 16 + lr;
        if (col < nstore) {
          float bv = bias[col];
          #pragma unroll
          for (int reg = 0; reg < 4; ++reg) {
            size_t m = m0 + wm * 64 + mi * 16 + quad * 4 + reg;
            ((__hip_bfloat16*)Cv)[m * ldc + col] =
                __float2bfloat16(acc[mi][ni][reg] + bv);
          }
        }
      }
    }
  } else {
    const int n4 = (int)(m0 >> 12), hw0 = (int)(m0 & 4095);
    for (int qc = 0; qc < 4; ++qc) {
      __syncthreads();
      if (wn == (qc >> 1)) {
        #pragma unroll
        for (int nis = 0; nis < 2; ++nis) {
          int ni = 2 * (qc & 1) + nis;
          int col = n0 + wn * 64 + ni * 16 + lr;
          float bv = bias[col];
          int cl = nis * 16 + lr;
          #pragma unroll
          for (int mi = 0; mi < 4; ++mi)
            #pragma unroll
            for (int reg = 0; reg < 4; ++reg) {
              int ml = wm * 64 + mi * 16 + quad * 4 + reg;
              tb[cl * 129 + ml] = acc[mi][ni][reg] + bv;
            }
        }
      }
      __syncthreads();
      #pragma unroll
      for (int r = 0; r < 4; ++r) {
        int f4i = t + r * 256;
        int row = f4i >> 5, mc = (f4i & 31) * 4;
        int co = n0 + qc * 32 + row;
        float4 v;
        v.x = tb[row * 129 + mc + 0];
        v.y = tb[row * 129 + mc + 1];
        v.z = tb[row * 129 + mc + 2];
        v.w = tb[row * 129 + mc + 3];
        *(float4*)&((float*)Cv)[(size_t)(n4 * 256 + co) * 4096 + hw0 + mc] = v;
      }
    }
  }
}

// ---------------- depthwise 3x3: block per (n,c) plane, fp32 x -> bf16 y ----
__global__ __launch_bounds__(256) void dwconv_k(
    const float* __restrict__ x, const float* __restrict__ dw_w,
    const float* __restrict__ dw_b, __hip_bfloat16* __restrict__ y)
{
  __shared__ float pl[4096];            // 64x64 plane
  const int bc = blockIdx.x;
  const int n4 = bc >> 8, c = bc & 255;
  const int t = threadIdx.x;
  const float* xc = x + (size_t)n4 * 1048576 + (size_t)c * 4096;
  #pragma unroll
  for (int r = 0; r < 4; ++r) {
    int idx4 = t + r * 256;
    *(float4*)&pl[idx4 * 4] = *(const float4*)&xc[idx4 * 4];
  }
  float wv[9];
  #pragma unroll
  for (int i = 0; i < 9; ++i) wv[i] = dw_w[c * 9 + i];
  const float bb = dw_b[c];
  __syncthreads();
  __hip_bfloat16* yc = y + (size_t)(n4 * 256 + c) * 4096;
  #pragma unroll 4
  for (int r = 0; r < 16; ++r) {
    int px = t + r * 256;
    int h = px >> 6, w = px & 63;
    float s = bb;
    #pragma unroll
    for (int dh = -1; dh <= 1; ++dh) {
      int hh = h + dh;
      if ((unsigned)hh >= 64u) continue;
      #pragma unroll
      for (int dw = -1; dw <= 1; ++dw) {
        int ww = w + dw;
        if ((unsigned)ww >= 64u) continue;
        s = fmaf(pl[hh * 64 + ww], wv[(dh + 1) * 3 + (dw + 1)], s);
      }
    }
    yc[px] = __float2bfloat16(s);
  }
}

// ---------------- LayerNorm(C) + GELU v3: 1024 threads/block ----------------
// block = one image row (64 px), 16 waves/CU. y bf16 NCHW -> x1 bf16 [pix][c].
__global__ __launch_bounds__(1024) void ln_k(
    const __hip_bfloat16* __restrict__ y, const float* __restrict__ ln_g,
    const float* __restrict__ ln_b, __hip_bfloat16* __restrict__ x1)
{
  __shared__ unsigned short ys[256 * 66];       // 33792 B
  __shared__ float gs[256], bs2[256];
  __shared__ float ps[16][64], pq[16][64], mu_s[64], rs_s[64];
  const int blk = blockIdx.x;                   // n4*64 + h
  const int n4 = blk >> 6, h = blk & 63;
  const int t = threadIdx.x;                    // 0..1023

  if (t < 256) { gs[t] = ln_g[t]; bs2[t] = ln_b[t]; }

  // phase 1: coalesced uint4 loads (8 bf16 along w) -> ys[c][w]
  const __hip_bfloat16* yb = y + (size_t)n4 * 1048576 + h * 64;
  #pragma unroll
  for (int r = 0; r < 2; ++r) {
    int idx = t + r * 1024;           // 2048 tasks: c = idx>>3, w8 = idx&7
    int c = idx >> 3, w8 = idx & 7;
    uint4 u = *(const uint4*)(yb + (size_t)c * 4096 + w8 * 8);
    unsigned* d = (unsigned*)&ys[c * 66 + w8 * 8];
    d[0] = u.x; d[1] = u.y; d[2] = u.z; d[3] = u.w;
  }
  __syncthreads();

  // phase 2: per-pixel partial sums (16 threads per pixel, 16 ch each)
  const int w = t & 63, q = t >> 6;             // q in [0,16)
  {
    float s1 = 0.f, s2 = 0.f;
    #pragma unroll
    for (int i = 0; i < 16; ++i) {
      float v = us2f(ys[(q * 16 + i) * 66 + w]);
      s1 += v; s2 = fmaf(v, v, s2);
    }
    ps[q][w] = s1; pq[q][w] = s2;
  }
  __syncthreads();
  if (t < 64) {
    float a = 0.f, b = 0.f;
    #pragma unroll
    for (int j = 0; j < 16; ++j) { a += ps[j][t]; b += pq[j][t]; }
    float mu = a * (1.f / 256.f);
    mu_s[t] = mu;
    rs_s[t] = rsqrtf(b * (1.f / 256.f) - mu * mu + 1e-5f);
  }
  __syncthreads();

  // phase 3: normalize + GELU in place (thread owns 16 channels at pixel w)
  const float mu = mu_s[w], rs = rs_s[w];
  #pragma unroll
  for (int i = 0; i < 16; ++i) {
    int c = q * 16 + i;
    float v = us2f(ys[c * 66 + w]);
    float yv = fmaf((v - mu) * rs, gs[c], bs2[c]);
    float ge = 0.5f * yv * (1.f + erff(yv * 0.70710678f));
    ys[c * 66 + w] = f2bf(ge);
  }
  __syncthreads();

  // phase 4: transposed coalesced stores to x1 [pix][c]
  const size_t row0 = ((size_t)n4 * 4096 + (size_t)h * 64) * 256;
  #pragma unroll
  for (int r = 0; r < 2; ++r) {
    int idx = t + r * 1024;           // 2048: pix = idx>>5, co8 = idx&31
    int pix = idx >> 5, co8 = idx & 31;
    unsigned short v0 = ys[(co8 * 8 + 0) * 66 + pix];
    unsigned short v1 = ys[(co8 * 8 + 1) * 66 + pix];
    unsigned short v2 = ys[(co8 * 8 + 2) * 66 + pix];
    unsigned short v3 = ys[(co8 * 8 + 3) * 66 + pix];
    unsigned short v4 = ys[(co8 * 8 + 4) * 66 + pix];
    unsigned short v5 = ys[(co8 * 8 + 5) * 66 + pix];
    unsigned short v6 = ys[(co8 * 8 + 6) * 66 + pix];
    unsigned short v7 = ys[(co8 * 8 + 7) * 66 + pix];
    uint4 u;
    u.x = (unsigned)v0 | ((unsigned)v1 << 16);
    u.y = (unsigned)v2 | ((unsigned)v3 << 16);
    u.z = (unsigned)v4 | ((unsigned)v5 << 16);
    u.w = (unsigned)v6 | ((unsigned)v7 << 16);
    *(uint4*)&x1[row0 + (size_t)pix * 256 + co8 * 8] = u;
  }
}

// ---------------- deformable sampling (swizzled; bf16 xpu; om via LDS) ------
__global__ __launch_bounds__(256) void sample_k(
    const __hip_bfloat16* __restrict__ xpu, const __hip_bfloat16* __restrict__ om,
    __hip_bfloat16* __restrict__ samp)
{
  __shared__ unsigned short oms[16 * 448];   // 14336 B
  const int bid = blockIdx.x;                // 1024
  const int region = bid & 7;                // XCD under round-robin dispatch
  const int q = bid >> 3;                    // 0..127 within region
  const int pix0 = region * 2048 + q * 16;   // 16 consecutive pixels
  const int t = threadIdx.x;

  {  // stage om tile: 16 px * 448 bf16 = 896 uint4
    const uint4* gsrc = (const uint4*)(om + (size_t)pix0 * 448);
    uint4* ldst = (uint4*)oms;
    #pragma unroll
    for (int r = 0; r < 4; ++r) {
      int i = t + r * 256;
      if (i < 896) ldst[i] = gsrc[i];
    }
  }
  __syncthreads();

  const int g = t & 15;
  const int pl = t >> 4;
  const int pix = pix0 + pl;
  const int n4 = pix >> 12;
  const int hw = pix & 4095;
  const int h = hw >> 6, w = hw & 63;

  float mk[9];
  {
    const unsigned short* mp = &oms[pl * 448 + 288 + g * 9];
    float mx = -1e30f;
    #pragma unroll
    for (int p = 0; p < 9; ++p) { mk[p] = us2f(mp[p]); mx = fmaxf(mx, mk[p]); }
    float se = 0.f;
    #pragma unroll
    for (int p = 0; p < 9; ++p) { mk[p] = __expf(mk[p] - mx); se += mk[p]; }
    float inv = 1.f / se;
    #pragma unroll
    for (int p = 0; p < 9; ++p) mk[p] *= inv;
  }

  const unsigned short* op = &oms[pl * 448 + g * 18];
  const __hip_bfloat16* xpg = xpu + (g << 4);
  float ax[16];
  #pragma unroll
  for (int i = 0; i < 16; ++i) ax[i] = 0.f;

  auto corner = [&](int iy, int ix, float wt) {
    // padded coords: data nonzero iff 1<=iy<=64 && 1<=ix<=64
    if ((unsigned)(iy - 1) >= 64u || (unsigned)(ix - 1) >= 64u) return;
    const __hip_bfloat16* src =
        xpg + ((size_t)((n4 << 12) + (iy - 1) * 64 + (ix - 1)) << 8);
    uint4 u0 = *(const uint4*)src;
    uint4 u1 = *(const uint4*)(src + 8);
    const unsigned uu[8] = {u0.x, u0.y, u0.z, u0.w, u1.x, u1.y, u1.z, u1.w};
    #pragma unroll
    for (int i = 0; i < 8; ++i) {
      float lo = us2f((unsigned short)(uu[i] & 0xffff));
      float hi = us2f((unsigned short)(uu[i] >> 16));
      ax[2 * i + 0] = fmaf(wt, lo, ax[2 * i + 0]);
      ax[2 * i + 1] = fmaf(wt, hi, ax[2 * i + 1]);
    }
  };

  #pragma unroll
  for (int p = 0; p < 9; ++p) {
    float ox = us2f(op[2 * p]), oy = us2f(op[2 * p + 1]);
    float px = (float)(w + p / 3) + ox;    // padded-space coords
    float py = (float)(h + p % 3) + oy;
    float xf = floorf(px), yf = floorf(py);
    float wx = px - xf, wy = py - yf;
    int ix = (int)xf, iy = (int)yf;
    float m = mk[p];
    corner(iy,     ix,     (1.f - wy) * (1.f - wx) * m);
    corner(iy,     ix + 1, (1.f - wy) * wx * m);
    corner(iy + 1, ix,     wy * (1.f - wx) * m);
    corner(iy + 1, ix + 1, wy * wx * m);
  }

  unsigned short ub[16];
  #pragma unroll
  for (int i = 0; i < 16; ++i) ub[i] = f2bf(ax[i]);
  uint4* d4 = (uint4*)(samp + (size_t)pix * 256 + (g << 4));
  uint4 u0, u1;
  u0.x = (unsigned)ub[0] | ((unsigned)ub[1] << 16);
  u0.y = (unsigned)ub[2] | ((unsigned)ub[3] << 16);
  u0.z = (unsigned)ub[4] | ((unsigned)ub[5] << 16);
  u0.w = (unsigned)ub[6] | ((unsigned)ub[7] << 16);
  u1.x = (unsigned)ub[8] | ((unsigned)ub[9] << 16);
  u1.y = (unsigned)ub[10] | ((unsigned)ub[11] << 16);
  u1.z = (unsigned)ub[12] | ((unsigned)ub[13] << 16);
  u1.w = (unsigned)ub[14] | ((unsigned)ub[15] << 16);
  d4[0] = u0; d4[1] = u1;
}

extern "C" void kernel_launch(void* const* d_in, const int* in_sizes, int n_in,
                              void* d_out, int out_size, void* d_ws, size_t ws_size,
                              hipStream_t stream) {
  const float* x      = (const float*)d_in[0];
  const float* dw_w   = (const float*)d_in[1];
  const float* dw_b   = (const float*)d_in[2];
  const float* ln_g   = (const float*)d_in[3];
  const float* ln_b   = (const float*)d_in[4];
  const float* off_w  = (const float*)d_in[5];
  const float* off_b  = (const float*)d_in[6];
  const float* mask_w = (const float*)d_in[7];
  const float* mask_b = (const float*)d_in[8];
  const float* inp_w  = (const float*)d_in[9];
  const float* inp_b  = (const float*)d_in[10];
  const float* out_w  = (const float*)d_in[11];
  const float* out_b  = (const float*)d_in[12];
  float* out = (float*)d_out;

  char* w0 = (char*)d_ws;
  __hip_bfloat16* xpu  = (__hip_bfloat16*)(w0);               //  8,388,608 B
  __hip_bfloat16* y    = (__hip_bfloat16*)(w0 + 8388608);     //  8,388,608 B
  __hip_bfloat16* x1   = (__hip_bfloat16*)(w0 + 16777216);    //  8,388,608 B
  __hip_bfloat16* xT   = (__hip_bfloat16*)(w0 + 25165824);    //  8,388,608 B
  __hip_bfloat16* samp = xT;                                  // alias (xT dead)
  __hip_bfloat16* om   = (__hip_bfloat16*)(w0 + 33554432);    // 14,680,064 B
  __hip_bfloat16* BtI  = (__hip_bfloat16*)(w0 + 48234496);    //    131,072 B
  __hip_bfloat16* BtOM = (__hip_bfloat16*)(w0 + 48365568);    //    262,144 B
  __hip_bfloat16* BtO  = (__hip_bfloat16*)(w0 + 48627712);    //    131,072 B
  float*          bOM  = (float*)(w0 + 48758784);             //      2,048 B
  if (ws_size < 48760832) return;

  prep_k<<<1024, 256, 0, stream>>>(inp_w, off_w, off_b, mask_w, mask_b, out_w,
                                   BtI, BtOM, BtO, bOM);
  xt_k<<<dim3(64, 8, 4), 256, 0, stream>>>(x, xT);
  gemm_mfma<2><<<dim3(2, 128), 256, 0, stream>>>(xT, BtI, inp_b, xpu, 256, 256);
  dwconv_k<<<1024, 256, 0, stream>>>(x, dw_w, dw_b, y);
  ln_k<<<256, 1024, 0, stream>>>(y, ln_g, ln_b, x1);
  gemm_mfma<2><<<dim3(4, 128), 256, 0, stream>>>(x1, BtOM, bOM, om, 448, 432);
  sample_k<<<1024, 256, 0, stream>>>(xpu, om, samp);
  gemm_mfma<3><<<dim3(2, 128), 256, 0, stream>>>(samp, BtO, out_b, out, 0, 256);
}

// Round 7
// 168.650 us; speedup vs baseline: 1.1908x; 1.0261x over previous
//
#include <hip/hip_runtime.h>
#include <hip/hip_bf16.h>
#include <math.h>

// R7: 64x64 GEMM tiles (4+ blocks/CU), gemmI+gemmOM merged. 7 dispatches.

using bf16x8 = __attribute__((ext_vector_type(8))) short;
using f32x4  = __attribute__((ext_vector_type(4))) float;

#define GLOBAL_AS __attribute__((address_space(1)))
#define LDS_AS    __attribute__((address_space(3)))

static __device__ inline void g2lds16(const void* g, void* l) {
  __builtin_amdgcn_global_load_lds((const GLOBAL_AS int*)g, (LDS_AS int*)l, 16, 0, 0);
}
static __device__ inline unsigned short f2bf(float v) {
  __hip_bfloat16 b = __float2bfloat16(v);
  return *reinterpret_cast<unsigned short*>(&b);
}
static __device__ inline float us2f(unsigned short u) {
  union { unsigned u; float f; } c; c.u = ((unsigned)u) << 16; return c.f;
}

// ---------------- weight prep: W[k][n] fp32 -> Bt[n][k] bf16 (+pad) ---------
__global__ __launch_bounds__(256) void prep_k(
    const float* __restrict__ inp_w, const float* __restrict__ off_w,
    const float* __restrict__ off_b, const float* __restrict__ mask_w,
    const float* __restrict__ mask_b, const float* __restrict__ out_w,
    __hip_bfloat16* __restrict__ BtI, __hip_bfloat16* __restrict__ BtOM,
    __hip_bfloat16* __restrict__ BtO, float* __restrict__ bOM)
{
  int b = blockIdx.x, t = threadIdx.x;   // t = k index
  if (b < 256) {
    int n = b;
    BtI[n * 256 + t] = __float2bfloat16(inp_w[t * 256 + n]);
  } else if (b < 768) {
    int n = b - 256;
    float v = 0.f;
    if (n < 288) v = off_w[t * 288 + n];
    else if (n < 432) v = mask_w[t * 144 + (n - 288)];
    BtOM[n * 256 + t] = __float2bfloat16(v);
    if (b == 256) {
      for (int idx = t; idx < 512; idx += 256) {
        float bv = (idx < 288) ? off_b[idx] : ((idx < 432) ? mask_b[idx - 288] : 0.f);
        bOM[idx] = bv;
      }
    }
  } else {
    int n = b - 768;
    BtO[n * 256 + t] = __float2bfloat16(out_w[t * 256 + n]);
  }
}

// ---------------- x NCHW fp32 -> xT [pix][c] bf16 ---------------------------
__global__ __launch_bounds__(256) void xt_k(const float* __restrict__ x,
                                            __hip_bfloat16* __restrict__ xT) {
  __shared__ float tile[32][65];
  const int hw0 = blockIdx.x * 64, c0 = blockIdx.y * 32, n4 = blockIdx.z;
  const int t = threadIdx.x;
  #pragma unroll
  for (int r = 0; r < 8; ++r) {
    int idx = t + r * 256;
    int cl = idx >> 6, wl = idx & 63;
    tile[cl][wl] = x[(size_t)n4 * 1048576 + (size_t)(c0 + cl) * 4096 + hw0 + wl];
  }
  __syncthreads();
  #pragma unroll
  for (int r = 0; r < 2; ++r) {
    int idx = t + r * 256;           // 512 tasks = 64 pix * 8 cquads
    int pixl = idx >> 3, cq = idx & 7;
    unsigned short b0 = f2bf(tile[cq * 4 + 0][pixl]);
    unsigned short b1 = f2bf(tile[cq * 4 + 1][pixl]);
    unsigned short b2 = f2bf(tile[cq * 4 + 2][pixl]);
    unsigned short b3 = f2bf(tile[cq * 4 + 3][pixl]);
    uint2 u;
    u.x = (unsigned)b0 | ((unsigned)b1 << 16);
    u.y = (unsigned)b2 | ((unsigned)b3 << 16);
    *(uint2*)&xT[((size_t)n4 * 4096 + hw0 + pixl) * 256 + c0 + cq * 4] = u;
  }
}

// ---------------- 64x64 MFMA GEMM core (shared by both GEMM kernels) --------
// A bf16 [m][256], Bt bf16 [n][256]; 4 waves 2x2; acc[2][2] f32x4.
struct G64 {
  f32x4 acc[2][2];
  int wave, lane, quad, lr, wm, wn;
};

static __device__ inline void g64_loop(
    G64& g, const __hip_bfloat16* __restrict__ A,
    const __hip_bfloat16* __restrict__ Bt, size_t m0, int n0,
    short* As, short* Bs, int t)
{
  #pragma unroll
  for (int i = 0; i < 2; ++i)
    #pragma unroll
    for (int j = 0; j < 2; ++j)
      g.acc[i][j] = (f32x4){0.f, 0.f, 0.f, 0.f};
  const int row = t >> 2, kq = t & 3;
  for (int kt = 0; kt < 256; kt += 32) {
    g2lds16(A + (m0 + row) * 256 + kt + kq * 8, (char*)As + t * 16);
    g2lds16(Bt + (size_t)(n0 + row) * 256 + kt + kq * 8, (char*)Bs + t * 16);
    __syncthreads();
    bf16x8 bfv[2];
    #pragma unroll
    for (int ni = 0; ni < 2; ++ni)
      bfv[ni] = *(const bf16x8*)&Bs[(g.wn * 32 + ni * 16 + g.lr) * 32 + g.quad * 8];
    #pragma unroll
    for (int mi = 0; mi < 2; ++mi) {
      bf16x8 af = *(const bf16x8*)&As[(g.wm * 32 + mi * 16 + g.lr) * 32 + g.quad * 8];
      #pragma unroll
      for (int ni = 0; ni < 2; ++ni)
        g.acc[mi][ni] = __builtin_amdgcn_mfma_f32_16x16x32_bf16(af, bfv[ni], g.acc[mi][ni], 0, 0, 0);
    }
    __syncthreads();
  }
}

// ---------------- combined input-proj + offset/mask GEMM --------------------
__global__ __launch_bounds__(256) void gemm_iom(
    const __hip_bfloat16* __restrict__ xT, const __hip_bfloat16* __restrict__ x1,
    const __hip_bfloat16* __restrict__ BtI, const __hip_bfloat16* __restrict__ BtOM,
    const float* __restrict__ inp_b, const float* __restrict__ bOM,
    __hip_bfloat16* __restrict__ xpu, __hip_bfloat16* __restrict__ om)
{
  __shared__ __align__(16) char smem[8192];
  short* As = (short*)smem;
  short* Bs = (short*)(smem + 4096);
  const int t = threadIdx.x;
  const int bx = blockIdx.x;
  const size_t m0 = (size_t)blockIdx.y * 64;

  const __hip_bfloat16* A;  const __hip_bfloat16* Bt;
  const float* bias;        __hip_bfloat16* C;
  int ldc, nst, n0;
  if (bx < 4) { A = xT; Bt = BtI;  bias = inp_b; C = xpu; ldc = 256; nst = 256; n0 = bx * 64; }
  else        { A = x1; Bt = BtOM; bias = bOM;   C = om;  ldc = 448; nst = 432; n0 = (bx - 4) * 64; }

  G64 g;
  g.wave = t >> 6; g.lane = t & 63; g.quad = g.lane >> 4; g.lr = g.lane & 15;
  g.wm = g.wave >> 1; g.wn = g.wave & 1;
  g64_loop(g, A, Bt, m0, n0, As, Bs, t);

  #pragma unroll
  for (int mi = 0; mi < 2; ++mi) {
    #pragma unroll
    for (int ni = 0; ni < 2; ++ni) {
      int col = n0 + g.wn * 32 + ni * 16 + g.lr;
      if (col < nst) {
        float bv = bias[col];
        #pragma unroll
        for (int reg = 0; reg < 4; ++reg) {
          size_t m = m0 + g.wm * 32 + mi * 16 + g.quad * 4 + reg;
          C[m * ldc + col] = __float2bfloat16(g.acc[mi][ni][reg] + bv);
        }
      }
    }
  }
}

// ---------------- output-proj GEMM -> fp32 NCHW -----------------------------
__global__ __launch_bounds__(256) void gemm_o(
    const __hip_bfloat16* __restrict__ samp, const __hip_bfloat16* __restrict__ BtO,
    const float* __restrict__ out_b, float* __restrict__ out)
{
  __shared__ __align__(16) char smem[8448];
  short* As = (short*)smem;
  short* Bs = (short*)(smem + 4096);
  float* tb = (float*)smem;            // epilogue reuse: [32][65] fp32 = 8320 B
  const int t = threadIdx.x;
  const int n0 = blockIdx.x * 64;
  const size_t m0 = (size_t)blockIdx.y * 64;

  G64 g;
  g.wave = t >> 6; g.lane = t & 63; g.quad = g.lane >> 4; g.lr = g.lane & 15;
  g.wm = g.wave >> 1; g.wn = g.wave & 1;
  g64_loop(g, samp, BtO, m0, n0, As, Bs, t);

  const int n4 = (int)(m0 >> 12), hw0 = (int)(m0 & 4095);
  for (int qc = 0; qc < 2; ++qc) {
    __syncthreads();
    if (g.wn == qc) {
      #pragma unroll
      for (int ni = 0; ni < 2; ++ni) {
        int cl = ni * 16 + g.lr;
        float bv = out_b[n0 + qc * 32 + cl];
        #pragma unroll
        for (int mi = 0; mi < 2; ++mi)
          #pragma unroll
          for (int reg = 0; reg < 4; ++reg)
            tb[cl * 65 + g.wm * 32 + mi * 16 + g.quad * 4 + reg] =
                g.acc[mi][ni][reg] + bv;
      }
    }
    __syncthreads();
    #pragma unroll
    for (int r = 0; r < 2; ++r) {
      int idx = t + r * 256;           // 512 = 32 cols * 16 m-quads
      int row = idx >> 4, mc = (idx & 15) * 4;
      int co = n0 + qc * 32 + row;
      float4 v;
      v.x = tb[row * 65 + mc + 0];
      v.y = tb[row * 65 + mc + 1];
      v.z = tb[row * 65 + mc + 2];
      v.w = tb[row * 65 + mc + 3];
      *(float4*)&out[(size_t)(n4 * 256 + co) * 4096 + hw0 + mc] = v;
    }
  }
}

// ---------------- depthwise 3x3: block per (n,c) plane, fp32 x -> bf16 y ----
__global__ __launch_bounds__(256) void dwconv_k(
    const float* __restrict__ x, const float* __restrict__ dw_w,
    const float* __restrict__ dw_b, __hip_bfloat16* __restrict__ y)
{
  __shared__ float pl[4096];            // 64x64 plane
  const int bc = blockIdx.x;
  const int n4 = bc >> 8, c = bc & 255;
  const int t = threadIdx.x;
  const float* xc = x + (size_t)n4 * 1048576 + (size_t)c * 4096;
  #pragma unroll
  for (int r = 0; r < 4; ++r) {
    int idx4 = t + r * 256;
    *(float4*)&pl[idx4 * 4] = *(const float4*)&xc[idx4 * 4];
  }
  float wv[9];
  #pragma unroll
  for (int i = 0; i < 9; ++i) wv[i] = dw_w[c * 9 + i];
  const float bb = dw_b[c];
  __syncthreads();
  __hip_bfloat16* yc = y + (size_t)(n4 * 256 + c) * 4096;
  #pragma unroll 4
  for (int r = 0; r < 16; ++r) {
    int px = t + r * 256;
    int h = px >> 6, w = px & 63;
    float s = bb;
    #pragma unroll
    for (int dh = -1; dh <= 1; ++dh) {
      int hh = h + dh;
      if ((unsigned)hh >= 64u) continue;
      #pragma unroll
      for (int dw = -1; dw <= 1; ++dw) {
        int ww = w + dw;
        if ((unsigned)ww >= 64u) continue;
        s = fmaf(pl[hh * 64 + ww], wv[(dh + 1) * 3 + (dw + 1)], s);
      }
    }
    yc[px] = __float2bfloat16(s);
  }
}

// ---------------- LayerNorm(C) + GELU: 1024 threads/block -------------------
__global__ __launch_bounds__(1024) void ln_k(
    const __hip_bfloat16* __restrict__ y, const float* __restrict__ ln_g,
    const float* __restrict__ ln_b, __hip_bfloat16* __restrict__ x1)
{
  __shared__ unsigned short ys[256 * 66];       // 33792 B
  __shared__ float gs[256], bs2[256];
  __shared__ float ps[16][64], pq[16][64], mu_s[64], rs_s[64];
  const int blk = blockIdx.x;                   // n4*64 + h
  const int n4 = blk >> 6, h = blk & 63;
  const int t = threadIdx.x;                    // 0..1023

  if (t < 256) { gs[t] = ln_g[t]; bs2[t] = ln_b[t]; }

  const __hip_bfloat16* yb = y + (size_t)n4 * 1048576 + h * 64;
  #pragma unroll
  for (int r = 0; r < 2; ++r) {
    int idx = t + r * 1024;           // 2048 tasks: c = idx>>3, w8 = idx&7
    int c = idx >> 3, w8 = idx & 7;
    uint4 u = *(const uint4*)(yb + (size_t)c * 4096 + w8 * 8);
    unsigned* d = (unsigned*)&ys[c * 66 + w8 * 8];
    d[0] = u.x; d[1] = u.y; d[2] = u.z; d[3] = u.w;
  }
  __syncthreads();

  const int w = t & 63, q = t >> 6;             // q in [0,16)
  {
    float s1 = 0.f, s2 = 0.f;
    #pragma unroll
    for (int i = 0; i < 16; ++i) {
      float v = us2f(ys[(q * 16 + i) * 66 + w]);
      s1 += v; s2 = fmaf(v, v, s2);
    }
    ps[q][w] = s1; pq[q][w] = s2;
  }
  __syncthreads();
  if (t < 64) {
    float a = 0.f, b = 0.f;
    #pragma unroll
    for (int j = 0; j < 16; ++j) { a += ps[j][t]; b += pq[j][t]; }
    float mu = a * (1.f / 256.f);
    mu_s[t] = mu;
    rs_s[t] = rsqrtf(b * (1.f / 256.f) - mu * mu + 1e-5f);
  }
  __syncthreads();

  const float mu = mu_s[w], rs = rs_s[w];
  #pragma unroll
  for (int i = 0; i < 16; ++i) {
    int c = q * 16 + i;
    float v = us2f(ys[c * 66 + w]);
    float yv = fmaf((v - mu) * rs, gs[c], bs2[c]);
    float ge = 0.5f * yv * (1.f + erff(yv * 0.70710678f));
    ys[c * 66 + w] = f2bf(ge);
  }
  __syncthreads();

  const size_t row0 = ((size_t)n4 * 4096 + (size_t)h * 64) * 256;
  #pragma unroll
  for (int r = 0; r < 2; ++r) {
    int idx = t + r * 1024;           // 2048: pix = idx>>5, co8 = idx&31
    int pix = idx >> 5, co8 = idx & 31;
    unsigned short v0 = ys[(co8 * 8 + 0) * 66 + pix];
    unsigned short v1 = ys[(co8 * 8 + 1) * 66 + pix];
    unsigned short v2 = ys[(co8 * 8 + 2) * 66 + pix];
    unsigned short v3 = ys[(co8 * 8 + 3) * 66 + pix];
    unsigned short v4 = ys[(co8 * 8 + 4) * 66 + pix];
    unsigned short v5 = ys[(co8 * 8 + 5) * 66 + pix];
    unsigned short v6 = ys[(co8 * 8 + 6) * 66 + pix];
    unsigned short v7 = ys[(co8 * 8 + 7) * 66 + pix];
    uint4 u;
    u.x = (unsigned)v0 | ((unsigned)v1 << 16);
    u.y = (unsigned)v2 | ((unsigned)v3 << 16);
    u.z = (unsigned)v4 | ((unsigned)v5 << 16);
    u.w = (unsigned)v6 | ((unsigned)v7 << 16);
    *(uint4*)&x1[row0 + (size_t)pix * 256 + co8 * 8] = u;
  }
}

// ---------------- deformable sampling (swizzled; bf16 xpu; om via LDS) ------
__global__ __launch_bounds__(256) void sample_k(
    const __hip_bfloat16* __restrict__ xpu, const __hip_bfloat16* __restrict__ om,
    __hip_bfloat16* __restrict__ samp)
{
  __shared__ unsigned short oms[16 * 448];   // 14336 B
  const int bid = blockIdx.x;                // 1024
  const int region = bid & 7;                // XCD under round-robin dispatch
  const int q = bid >> 3;                    // 0..127 within region
  const int pix0 = region * 2048 + q * 16;   // 16 consecutive pixels
  const int t = threadIdx.x;

  {  // stage om tile: 16 px * 448 bf16 = 896 uint4
    const uint4* gsrc = (const uint4*)(om + (size_t)pix0 * 448);
    uint4* ldst = (uint4*)oms;
    #pragma unroll
    for (int r = 0; r < 4; ++r) {
      int i = t + r * 256;
      if (i < 896) ldst[i] = gsrc[i];
    }
  }
  __syncthreads();

  const int g = t & 15;
  const int pl = t >> 4;
  const int pix = pix0 + pl;
  const int n4 = pix >> 12;
  const int hw = pix & 4095;
  const int h = hw >> 6, w = hw & 63;

  float mk[9];
  {
    const unsigned short* mp = &oms[pl * 448 + 288 + g * 9];
    float mx = -1e30f;
    #pragma unroll
    for (int p = 0; p < 9; ++p) { mk[p] = us2f(mp[p]); mx = fmaxf(mx, mk[p]); }
    float se = 0.f;
    #pragma unroll
    for (int p = 0; p < 9; ++p) { mk[p] = __expf(mk[p] - mx); se += mk[p]; }
    float inv = 1.f / se;
    #pragma unroll
    for (int p = 0; p < 9; ++p) mk[p] *= inv;
  }

  const unsigned short* op = &oms[pl * 448 + g * 18];
  const __hip_bfloat16* xpg = xpu + (g << 4);
  float ax[16];
  #pragma unroll
  for (int i = 0; i < 16; ++i) ax[i] = 0.f;

  auto corner = [&](int iy, int ix, float wt) {
    if ((unsigned)(iy - 1) >= 64u || (unsigned)(ix - 1) >= 64u) return;
    const __hip_bfloat16* src =
        xpg + ((size_t)((n4 << 12) + (iy - 1) * 64 + (ix - 1)) << 8);
    uint4 u0 = *(const uint4*)src;
    uint4 u1 = *(const uint4*)(src + 8);
    const unsigned uu[8] = {u0.x, u0.y, u0.z, u0.w, u1.x, u1.y, u1.z, u1.w};
    #pragma unroll
    for (int i = 0; i < 8; ++i) {
      float lo = us2f((unsigned short)(uu[i] & 0xffff));
      float hi = us2f((unsigned short)(uu[i] >> 16));
      ax[2 * i + 0] = fmaf(wt, lo, ax[2 * i + 0]);
      ax[2 * i + 1] = fmaf(wt, hi, ax[2 * i + 1]);
    }
  };

  #pragma unroll
  for (int p = 0; p < 9; ++p) {
    float ox = us2f(op[2 * p]), oy = us2f(op[2 * p + 1]);
    float px = (float)(w + p / 3) + ox;
    float py = (float)(h + p % 3) + oy;
    float xf = floorf(px), yf = floorf(py);
    float wx = px - xf, wy = py - yf;
    int ix = (int)xf, iy = (int)yf;
    float m = mk[p];
    corner(iy,     ix,     (1.f - wy) * (1.f - wx) * m);
    corner(iy,     ix + 1, (1.f - wy) * wx * m);
    corner(iy + 1, ix,     wy * (1.f - wx) * m);
    corner(iy + 1, ix + 1, wy * wx * m);
  }

  unsigned short ub[16];
  #pragma unroll
  for (int i = 0; i < 16; ++i) ub[i] = f2bf(ax[i]);
  uint4* d4 = (uint4*)(samp + (size_t)pix * 256 + (g << 4));
  uint4 u0, u1;
  u0.x = (unsigned)ub[0] | ((unsigned)ub[1] << 16);
  u0.y = (unsigned)ub[2] | ((unsigned)ub[3] << 16);
  u0.z = (unsigned)ub[4] | ((unsigned)ub[5] << 16);
  u0.w = (unsigned)ub[6] | ((unsigned)ub[7] << 16);
  u1.x = (unsigned)ub[8] | ((unsigned)ub[9] << 16);
  u1.y = (unsigned)ub[10] | ((unsigned)ub[11] << 16);
  u1.z = (unsigned)ub[12] | ((unsigned)ub[13] << 16);
  u1.w = (unsigned)ub[14] | ((unsigned)ub[15] << 16);
  d4[0] = u0; d4[1] = u1;
}

extern "C" void kernel_launch(void* const* d_in, const int* in_sizes, int n_in,
                              void* d_out, int out_size, void* d_ws, size_t ws_size,
                              hipStream_t stream) {
  const float* x      = (const float*)d_in[0];
  const float* dw_w   = (const float*)d_in[1];
  const float* dw_b   = (const float*)d_in[2];
  const float* ln_g   = (const float*)d_in[3];
  const float* ln_b   = (const float*)d_in[4];
  const float* off_w  = (const float*)d_in[5];
  const float* off_b  = (const float*)d_in[6];
  const float* mask_w = (const float*)d_in[7];
  const float* mask_b = (const float*)d_in[8];
  const float* inp_w  = (const float*)d_in[9];
  const float* inp_b  = (const float*)d_in[10];
  const float* out_w  = (const float*)d_in[11];
  const float* out_b  = (const float*)d_in[12];
  float* out = (float*)d_out;

  char* w0 = (char*)d_ws;
  __hip_bfloat16* xpu  = (__hip_bfloat16*)(w0);               //  8,388,608 B
  __hip_bfloat16* y    = (__hip_bfloat16*)(w0 + 8388608);     //  8,388,608 B
  __hip_bfloat16* x1   = (__hip_bfloat16*)(w0 + 16777216);    //  8,388,608 B
  __hip_bfloat16* xT   = (__hip_bfloat16*)(w0 + 25165824);    //  8,388,608 B
  __hip_bfloat16* samp = xT;                                  // alias (xT dead)
  __hip_bfloat16* om   = (__hip_bfloat16*)(w0 + 33554432);    // 14,680,064 B
  __hip_bfloat16* BtI  = (__hip_bfloat16*)(w0 + 48234496);    //    131,072 B
  __hip_bfloat16* BtOM = (__hip_bfloat16*)(w0 + 48365568);    //    262,144 B
  __hip_bfloat16* BtO  = (__hip_bfloat16*)(w0 + 48627712);    //    131,072 B
  float*          bOM  = (float*)(w0 + 48758784);             //      2,048 B
  if (ws_size < 48760832) return;

  prep_k<<<1024, 256, 0, stream>>>(inp_w, off_w, off_b, mask_w, mask_b, out_w,
                                   BtI, BtOM, BtO, bOM);
  xt_k<<<dim3(64, 8, 4), 256, 0, stream>>>(x, xT);
  dwconv_k<<<1024, 256, 0, stream>>>(x, dw_w, dw_b, y);
  ln_k<<<256, 1024, 0, stream>>>(y, ln_g, ln_b, x1);
  gemm_iom<<<dim3(11, 256), 256, 0, stream>>>(xT, x1, BtI, BtOM, inp_b, bOM, xpu, om);
  sample_k<<<1024, 256, 0, stream>>>(xpu, om, samp);
  gemm_o<<<dim3(4, 256), 256, 0, stream>>>(samp, BtO, out_b, out);
}

// Round 8
// 163.347 us; speedup vs baseline: 1.2295x; 1.0325x over previous
//
#include <hip/hip_runtime.h>
#include <hip/hip_bf16.h>
#include <math.h>

// R8: megafused stage2 (dwconv+LN+GELU+OM-GEMM, x1/y never hit global),
// prep+xt merged. 5 dispatches.

using bf16x8 = __attribute__((ext_vector_type(8))) short;
using f32x4  = __attribute__((ext_vector_type(4))) float;

#define GLOBAL_AS __attribute__((address_space(1)))
#define LDS_AS    __attribute__((address_space(3)))

static __device__ inline void g2lds16(const void* g, void* l) {
  __builtin_amdgcn_global_load_lds((const GLOBAL_AS int*)g, (LDS_AS int*)l, 16, 0, 0);
}
static __device__ inline unsigned short f2bf(float v) {
  __hip_bfloat16 b = __float2bfloat16(v);
  return *reinterpret_cast<unsigned short*>(&b);
}
static __device__ inline float us2f(unsigned short u) {
  union { unsigned u; float f; } c; c.u = ((unsigned)u) << 16; return c.f;
}

// ---------------- prep (weights transpose->bf16) + x NCHW -> xT [pix][c] ----
__global__ __launch_bounds__(256) void prep_xt_k(
    const float* __restrict__ x,
    const float* __restrict__ inp_w, const float* __restrict__ off_w,
    const float* __restrict__ off_b, const float* __restrict__ mask_w,
    const float* __restrict__ mask_b, const float* __restrict__ out_w,
    __hip_bfloat16* __restrict__ BtI, __hip_bfloat16* __restrict__ BtOM,
    __hip_bfloat16* __restrict__ BtO, float* __restrict__ bOM,
    __hip_bfloat16* __restrict__ xT)
{
  __shared__ float tile[32][65];
  const int b = blockIdx.x, t = threadIdx.x;
  if (b < 1024) {
    if (b < 256) {
      int n = b;
      BtI[n * 256 + t] = __float2bfloat16(inp_w[t * 256 + n]);
    } else if (b < 768) {
      int n = b - 256;
      float v = 0.f;
      if (n < 288) v = off_w[t * 288 + n];
      else if (n < 432) v = mask_w[t * 144 + (n - 288)];
      BtOM[n * 256 + t] = __float2bfloat16(v);
      if (b == 256) {
        for (int idx = t; idx < 512; idx += 256) {
          float bv = (idx < 288) ? off_b[idx] : ((idx < 432) ? mask_b[idx - 288] : 0.f);
          bOM[idx] = bv;
        }
      }
    } else {
      int n = b - 768;
      BtO[n * 256 + t] = __float2bfloat16(out_w[t * 256 + n]);
    }
    return;
  }
  const int i = b - 1024;                 // 0..2047
  const int hw0 = (i & 63) * 64, c0 = ((i >> 6) & 7) * 32, n4 = i >> 9;
  #pragma unroll
  for (int r = 0; r < 8; ++r) {
    int idx = t + r * 256;
    int cl = idx >> 6, wl = idx & 63;
    tile[cl][wl] = x[(size_t)n4 * 1048576 + (size_t)(c0 + cl) * 4096 + hw0 + wl];
  }
  __syncthreads();
  #pragma unroll
  for (int r = 0; r < 2; ++r) {
    int idx = t + r * 256;                // 512 tasks = 64 pix * 8 cquads
    int pixl = idx >> 3, cq = idx & 7;
    unsigned short b0 = f2bf(tile[cq * 4 + 0][pixl]);
    unsigned short b1 = f2bf(tile[cq * 4 + 1][pixl]);
    unsigned short b2 = f2bf(tile[cq * 4 + 2][pixl]);
    unsigned short b3 = f2bf(tile[cq * 4 + 3][pixl]);
    uint2 u;
    u.x = (unsigned)b0 | ((unsigned)b1 << 16);
    u.y = (unsigned)b2 | ((unsigned)b3 << 16);
    *(uint2*)&xT[((size_t)n4 * 4096 + hw0 + pixl) * 256 + c0 + cq * 4] = u;
  }
}

// ---------------- 64x64 MFMA GEMM core --------------------------------------
struct G64 {
  f32x4 acc[2][2];
  int wave, lane, quad, lr, wm, wn;
};

static __device__ inline void g64_loop(
    G64& g, const __hip_bfloat16* __restrict__ A,
    const __hip_bfloat16* __restrict__ Bt, size_t m0, int n0,
    short* As, short* Bs, int t)
{
  #pragma unroll
  for (int i = 0; i < 2; ++i)
    #pragma unroll
    for (int j = 0; j < 2; ++j)
      g.acc[i][j] = (f32x4){0.f, 0.f, 0.f, 0.f};
  const int row = t >> 2, kq = t & 3;
  for (int kt = 0; kt < 256; kt += 32) {
    g2lds16(A + (m0 + row) * 256 + kt + kq * 8, (char*)As + t * 16);
    g2lds16(Bt + (size_t)(n0 + row) * 256 + kt + kq * 8, (char*)Bs + t * 16);
    __syncthreads();
    bf16x8 bfv[2];
    #pragma unroll
    for (int ni = 0; ni < 2; ++ni)
      bfv[ni] = *(const bf16x8*)&Bs[(g.wn * 32 + ni * 16 + g.lr) * 32 + g.quad * 8];
    #pragma unroll
    for (int mi = 0; mi < 2; ++mi) {
      bf16x8 af = *(const bf16x8*)&As[(g.wm * 32 + mi * 16 + g.lr) * 32 + g.quad * 8];
      #pragma unroll
      for (int ni = 0; ni < 2; ++ni)
        g.acc[mi][ni] = __builtin_amdgcn_mfma_f32_16x16x32_bf16(af, bfv[ni], g.acc[mi][ni], 0, 0, 0);
    }
    __syncthreads();
  }
}

// ---------------- input-proj GEMM: xT @ BtI -> xpu bf16 ---------------------
__global__ __launch_bounds__(256) void gemm_i(
    const __hip_bfloat16* __restrict__ xT, const __hip_bfloat16* __restrict__ BtI,
    const float* __restrict__ inp_b, __hip_bfloat16* __restrict__ xpu)
{
  __shared__ __align__(16) char smem[8192];
  short* As = (short*)smem;
  short* Bs = (short*)(smem + 4096);
  const int t = threadIdx.x;
  const int n0 = blockIdx.x * 64;
  const size_t m0 = (size_t)blockIdx.y * 64;

  G64 g;
  g.wave = t >> 6; g.lane = t & 63; g.quad = g.lane >> 4; g.lr = g.lane & 15;
  g.wm = g.wave >> 1; g.wn = g.wave & 1;
  g64_loop(g, xT, BtI, m0, n0, As, Bs, t);

  #pragma unroll
  for (int mi = 0; mi < 2; ++mi) {
    #pragma unroll
    for (int ni = 0; ni < 2; ++ni) {
      int col = n0 + g.wn * 32 + ni * 16 + g.lr;
      float bv = inp_b[col];
      #pragma unroll
      for (int reg = 0; reg < 4; ++reg) {
        size_t m = m0 + g.wm * 32 + mi * 16 + g.quad * 4 + reg;
        xpu[m * 256 + col] = __float2bfloat16(g.acc[mi][ni][reg] + bv);
      }
    }
  }
}

// ---------------- stage2: dwconv(bf16 xT) + LN + GELU + OM GEMM -------------
// block = one image row (64 px), 1024 threads. x1 lives only in LDS.
__global__ __launch_bounds__(1024) void stage2_k(
    const __hip_bfloat16* __restrict__ xT,
    const float* __restrict__ dw_w, const float* __restrict__ dw_b,
    const float* __restrict__ ln_g, const float* __restrict__ ln_b,
    const __hip_bfloat16* __restrict__ BtOM, const float* __restrict__ bOM,
    __hip_bfloat16* __restrict__ om)
{
  __shared__ __align__(16) char smem[62464];
  unsigned short* x1t = (unsigned short*)smem;                 // [64][264] 33792 B (persistent)
  unsigned short* xs  = (unsigned short*)(smem + 33792);       // [3][64][40] 15360 B
  float* wgt  = (float*)(smem + 33792 + 15360);                // [9][32] 1152 B
  float* psq  = (float*)(smem + 33792 + 15360 + 1152);         // ps[16*64]|pq[16*64] 8192 B
  float* murs = (float*)(smem + 33792 + 15360 + 1152 + 8192);  // mu[64]|rs[64] 512 B
  short* Bs   = (short*)(smem + 33792);                        // GEMM phase: [448][32] 28672 B

  const int blk = blockIdx.x;
  const int n4 = blk >> 6, h = blk & 63;
  const int t = threadIdx.x;
  const int w = t & 63, q = t >> 6;          // pixel w, channel-group q (0..15)

  float s1 = 0.f, s2 = 0.f;
  for (int chunk = 0; chunk < 8; ++chunk) {
    const int ch0 = chunk * 32;
    if (t < 768) {                           // stage xs: 3 rows x 64 px x 32 ch
      int r = t >> 8, i = t & 255;
      int px = i >> 2, cq = i & 3;
      int hh = h + r - 1;
      uint4 v = {0, 0, 0, 0};
      if ((unsigned)hh < 64u)
        v = *(const uint4*)(xT + ((size_t)n4 * 4096 + (size_t)hh * 64 + px) * 256 + ch0 + cq * 8);
      *(uint4*)&xs[(r * 64 + px) * 40 + cq * 8] = v;
    }
    if (t < 288) {                           // stage weights [p][lc]
      int p = t >> 5, lc = t & 31;
      wgt[p * 32 + lc] = dw_w[(ch0 + lc) * 9 + p];
    }
    __syncthreads();
    {                                        // conv: 2 channels per thread
      int c = ch0 + 2 * q;
      float a0 = dw_b[c], a1 = dw_b[c + 1];
      #pragma unroll
      for (int p = 0; p < 9; ++p) {
        int dh = p / 3, dwd = p % 3 - 1;
        int ww = w + dwd;
        if ((unsigned)ww < 64u) {
          unsigned xv = *(const unsigned*)&xs[(dh * 64 + ww) * 40 + 2 * q];
          float wa = wgt[p * 32 + 2 * q], wb = wgt[p * 32 + 2 * q + 1];
          a0 = fmaf(us2f((unsigned short)(xv & 0xffff)), wa, a0);
          a1 = fmaf(us2f((unsigned short)(xv >> 16)), wb, a1);
        }
      }
      s1 += a0 + a1;
      s2 = fmaf(a0, a0, fmaf(a1, a1, s2));
      unsigned pk = (unsigned)f2bf(a0) | ((unsigned)f2bf(a1) << 16);
      *(unsigned*)&x1t[w * 264 + c] = pk;
    }
    __syncthreads();                         // before next chunk overwrites xs
  }

  psq[q * 64 + w] = s1;
  psq[1024 + q * 64 + w] = s2;
  __syncthreads();
  if (t < 64) {
    float a = 0.f, b = 0.f;
    #pragma unroll
    for (int j = 0; j < 16; ++j) { a += psq[j * 64 + t]; b += psq[1024 + j * 64 + t]; }
    float mu = a * (1.f / 256.f);
    murs[t] = mu;
    murs[64 + t] = rsqrtf(b * (1.f / 256.f) - mu * mu + 1e-5f);
  }
  __syncthreads();
  {                                          // normalize + GELU in place
    float mu = murs[w], rs = murs[64 + w];
    #pragma unroll
    for (int chunk = 0; chunk < 8; ++chunk) {
      int c = chunk * 32 + 2 * q;
      unsigned pk = *(const unsigned*)&x1t[w * 264 + c];
      float v0 = us2f((unsigned short)(pk & 0xffff));
      float v1 = us2f((unsigned short)(pk >> 16));
      float y0 = fmaf((v0 - mu) * rs, ln_g[c], ln_b[c]);
      float y1 = fmaf((v1 - mu) * rs, ln_g[c + 1], ln_b[c + 1]);
      float g0 = 0.5f * y0 * (1.f + erff(y0 * 0.70710678f));
      float g1 = 0.5f * y1 * (1.f + erff(y1 * 0.70710678f));
      *(unsigned*)&x1t[w * 264 + c] = (unsigned)f2bf(g0) | ((unsigned)f2bf(g1) << 16);
    }
  }
  __syncthreads();

  // OM GEMM: M=64 (pixels), N=448 (432 valid), K=256. 16 waves = 4m x 4n.
  const int wave = t >> 6, lane = t & 63;
  const int quad = lane >> 4, lr = lane & 15;
  const int wm = wave >> 2, wn = wave & 3;
  f32x4 acc[7];
  #pragma unroll
  for (int i = 0; i < 7; ++i) acc[i] = (f32x4){0.f, 0.f, 0.f, 0.f};

  for (int kt = 0; kt < 256; kt += 32) {
    __syncthreads();                         // Bs reads from prev iter done
    {
      int col = t >> 2, kq = t & 3;
      g2lds16(BtOM + (size_t)col * 256 + kt + kq * 8, (char*)Bs + t * 16);
      int j = t + 1024;
      if (j < 1792) {
        col = j >> 2; kq = j & 3;
        g2lds16(BtOM + (size_t)col * 256 + kt + kq * 8, (char*)Bs + j * 16);
      }
    }
    __syncthreads();
    bf16x8 af = *(const bf16x8*)&x1t[(wm * 16 + lr) * 264 + kt + quad * 8];
    #pragma unroll
    for (int ni = 0; ni < 7; ++ni) {
      bf16x8 bf = *(const bf16x8*)&Bs[(wn * 112 + ni * 16 + lr) * 32 + quad * 8];
      acc[ni] = __builtin_amdgcn_mfma_f32_16x16x32_bf16(af, bf, acc[ni], 0, 0, 0);
    }
  }

  const size_t pix0 = (size_t)n4 * 4096 + (size_t)h * 64;
  #pragma unroll
  for (int ni = 0; ni < 7; ++ni) {
    int col = wn * 112 + ni * 16 + lr;
    if (col < 432) {
      float bv = bOM[col];
      #pragma unroll
      for (int reg = 0; reg < 4; ++reg) {
        int m = wm * 16 + quad * 4 + reg;
        om[(pix0 + m) * 448 + col] = __float2bfloat16(acc[ni][reg] + bv);
      }
    }
  }
}

// ---------------- deformable sampling (swizzled; bf16 xpu; om via LDS) ------
__global__ __launch_bounds__(256) void sample_k(
    const __hip_bfloat16* __restrict__ xpu, const __hip_bfloat16* __restrict__ om,
    __hip_bfloat16* __restrict__ samp)
{
  __shared__ unsigned short oms[16 * 448];   // 14336 B
  const int bid = blockIdx.x;                // 1024
  const int region = bid & 7;                // XCD under round-robin dispatch
  const int q = bid >> 3;                    // 0..127 within region
  const int pix0 = region * 2048 + q * 16;   // 16 consecutive pixels
  const int t = threadIdx.x;

  {  // stage om tile: 16 px * 448 bf16 = 896 uint4
    const uint4* gsrc = (const uint4*)(om + (size_t)pix0 * 448);
    uint4* ldst = (uint4*)oms;
    #pragma unroll
    for (int r = 0; r < 4; ++r) {
      int i = t + r * 256;
      if (i < 896) ldst[i] = gsrc[i];
    }
  }
  __syncthreads();

  const int g = t & 15;
  const int pl = t >> 4;
  const int pix = pix0 + pl;
  const int n4 = pix >> 12;
  const int hw = pix & 4095;
  const int h = hw >> 6, w = hw & 63;

  float mk[9];
  {
    const unsigned short* mp = &oms[pl * 448 + 288 + g * 9];
    float mx = -1e30f;
    #pragma unroll
    for (int p = 0; p < 9; ++p) { mk[p] = us2f(mp[p]); mx = fmaxf(mx, mk[p]); }
    float se = 0.f;
    #pragma unroll
    for (int p = 0; p < 9; ++p) { mk[p] = __expf(mk[p] - mx); se += mk[p]; }
    float inv = 1.f / se;
    #pragma unroll
    for (int p = 0; p < 9; ++p) mk[p] *= inv;
  }

  const unsigned short* op = &oms[pl * 448 + g * 18];
  const __hip_bfloat16* xpg = xpu + (g << 4);
  float ax[16];
  #pragma unroll
  for (int i = 0; i < 16; ++i) ax[i] = 0.f;

  auto corner = [&](int iy, int ix, float wt) {
    if ((unsigned)(iy - 1) >= 64u || (unsigned)(ix - 1) >= 64u) return;
    const __hip_bfloat16* src =
        xpg + ((size_t)((n4 << 12) + (iy - 1) * 64 + (ix - 1)) << 8);
    uint4 u0 = *(const uint4*)src;
    uint4 u1 = *(const uint4*)(src + 8);
    const unsigned uu[8] = {u0.x, u0.y, u0.z, u0.w, u1.x, u1.y, u1.z, u1.w};
    #pragma unroll
    for (int i = 0; i < 8; ++i) {
      float lo = us2f((unsigned short)(uu[i] & 0xffff));
      float hi = us2f((unsigned short)(uu[i] >> 16));
      ax[2 * i + 0] = fmaf(wt, lo, ax[2 * i + 0]);
      ax[2 * i + 1] = fmaf(wt, hi, ax[2 * i + 1]);
    }
  };

  #pragma unroll
  for (int p = 0; p < 9; ++p) {
    float ox = us2f(op[2 * p]), oy = us2f(op[2 * p + 1]);
    float px = (float)(w + p / 3) + ox;
    float py = (float)(h + p % 3) + oy;
    float xf = floorf(px), yf = floorf(py);
    float wx = px - xf, wy = py - yf;
    int ix = (int)xf, iy = (int)yf;
    float m = mk[p];
    corner(iy,     ix,     (1.f - wy) * (1.f - wx) * m);
    corner(iy,     ix + 1, (1.f - wy) * wx * m);
    corner(iy + 1, ix,     wy * (1.f - wx) * m);
    corner(iy + 1, ix + 1, wy * wx * m);
  }

  unsigned short ub[16];
  #pragma unroll
  for (int i = 0; i < 16; ++i) ub[i] = f2bf(ax[i]);
  uint4* d4 = (uint4*)(samp + (size_t)pix * 256 + (g << 4));
  uint4 u0, u1;
  u0.x = (unsigned)ub[0] | ((unsigned)ub[1] << 16);
  u0.y = (unsigned)ub[2] | ((unsigned)ub[3] << 16);
  u0.z = (unsigned)ub[4] | ((unsigned)ub[5] << 16);
  u0.w = (unsigned)ub[6] | ((unsigned)ub[7] << 16);
  u1.x = (unsigned)ub[8] | ((unsigned)ub[9] << 16);
  u1.y = (unsigned)ub[10] | ((unsigned)ub[11] << 16);
  u1.z = (unsigned)ub[12] | ((unsigned)ub[13] << 16);
  u1.w = (unsigned)ub[14] | ((unsigned)ub[15] << 16);
  d4[0] = u0; d4[1] = u1;
}

// ---------------- output-proj GEMM -> fp32 NCHW -----------------------------
__global__ __launch_bounds__(256) void gemm_o(
    const __hip_bfloat16* __restrict__ samp, const __hip_bfloat16* __restrict__ BtO,
    const float* __restrict__ out_b, float* __restrict__ out)
{
  __shared__ __align__(16) char smem[8448];
  short* As = (short*)smem;
  short* Bs = (short*)(smem + 4096);
  float* tb = (float*)smem;            // epilogue reuse: [32][65] fp32 = 8320 B
  const int t = threadIdx.x;
  const int n0 = blockIdx.x * 64;
  const size_t m0 = (size_t)blockIdx.y * 64;

  G64 g;
  g.wave = t >> 6; g.lane = t & 63; g.quad = g.lane >> 4; g.lr = g.lane & 15;
  g.wm = g.wave >> 1; g.wn = g.wave & 1;
  g64_loop(g, samp, BtO, m0, n0, As, Bs, t);

  const int n4 = (int)(m0 >> 12), hw0 = (int)(m0 & 4095);
  for (int qc = 0; qc < 2; ++qc) {
    __syncthreads();
    if (g.wn == qc) {
      #pragma unroll
      for (int ni = 0; ni < 2; ++ni) {
        int cl = ni * 16 + g.lr;
        float bv = out_b[n0 + qc * 32 + cl];
        #pragma unroll
        for (int mi = 0; mi < 2; ++mi)
          #pragma unroll
          for (int reg = 0; reg < 4; ++reg)
            tb[cl * 65 + g.wm * 32 + mi * 16 + g.quad * 4 + reg] =
                g.acc[mi][ni][reg] + bv;
      }
    }
    __syncthreads();
    #pragma unroll
    for (int r = 0; r < 2; ++r) {
      int idx = t + r * 256;           // 512 = 32 cols * 16 m-quads
      int row = idx >> 4, mc = (idx & 15) * 4;
      int co = n0 + qc * 32 + row;
      float4 v;
      v.x = tb[row * 65 + mc + 0];
      v.y = tb[row * 65 + mc + 1];
      v.z = tb[row * 65 + mc + 2];
      v.w = tb[row * 65 + mc + 3];
      *(float4*)&out[(size_t)(n4 * 256 + co) * 4096 + hw0 + mc] = v;
    }
  }
}

extern "C" void kernel_launch(void* const* d_in, const int* in_sizes, int n_in,
                              void* d_out, int out_size, void* d_ws, size_t ws_size,
                              hipStream_t stream) {
  const float* x      = (const float*)d_in[0];
  const float* dw_w   = (const float*)d_in[1];
  const float* dw_b   = (const float*)d_in[2];
  const float* ln_g   = (const float*)d_in[3];
  const float* ln_b   = (const float*)d_in[4];
  const float* off_w  = (const float*)d_in[5];
  const float* off_b  = (const float*)d_in[6];
  const float* mask_w = (const float*)d_in[7];
  const float* mask_b = (const float*)d_in[8];
  const float* inp_w  = (const float*)d_in[9];
  const float* inp_b  = (const float*)d_in[10];
  const float* out_w  = (const float*)d_in[11];
  const float* out_b  = (const float*)d_in[12];
  float* out = (float*)d_out;

  char* w0 = (char*)d_ws;
  __hip_bfloat16* xpu  = (__hip_bfloat16*)(w0);               //  8,388,608 B
  __hip_bfloat16* xT   = (__hip_bfloat16*)(w0 + 8388608);     //  8,388,608 B
  __hip_bfloat16* samp = xT;                                  // alias (xT dead by then)
  __hip_bfloat16* om   = (__hip_bfloat16*)(w0 + 16777216);    // 14,680,064 B
  __hip_bfloat16* BtI  = (__hip_bfloat16*)(w0 + 31457280);    //    131,072 B
  __hip_bfloat16* BtOM = (__hip_bfloat16*)(w0 + 31588352);    //    262,144 B
  __hip_bfloat16* BtO  = (__hip_bfloat16*)(w0 + 31850496);    //    131,072 B
  float*          bOM  = (float*)(w0 + 31981568);             //      2,048 B
  if (ws_size < 31983616) return;

  prep_xt_k<<<3072, 256, 0, stream>>>(x, inp_w, off_w, off_b, mask_w, mask_b,
                                      out_w, BtI, BtOM, BtO, bOM, xT);
  gemm_i<<<dim3(4, 256), 256, 0, stream>>>(xT, BtI, inp_b, xpu);
  stage2_k<<<256, 1024, 0, stream>>>(xT, dw_w, dw_b, ln_g, ln_b, BtOM, bOM, om);
  sample_k<<<1024, 256, 0, stream>>>(xpu, om, samp);
  gemm_o<<<dim3(4, 256), 256, 0, stream>>>(samp, BtO, out_b, out);
}